// Round 7
// baseline (2588.235 us; speedup 1.0000x reference)
//
#include <hip/hip_runtime.h>
#include <hip/hip_bf16.h>
#include <stdint.h>

// Problem constants
#define BATCH_ 256
#define SEQ_   128
#define DIN_   768
#define HID_   512
#define NG_    2048   // 4*HID
#define NCLS_  9

typedef unsigned short u16;
typedef unsigned int u32;
typedef unsigned long long u64;
typedef __attribute__((ext_vector_type(8))) short bf16x8;
typedef __attribute__((ext_vector_type(4))) float f32x4;

__device__ __forceinline__ float bf2f(u16 u) {
  return __builtin_bit_cast(float, (uint32_t)u << 16);
}
__device__ __forceinline__ u16 f2bf(float f) {
  uint32_t x = __builtin_bit_cast(uint32_t, f);
  uint32_t r = (x + 0x7fffu + ((x >> 16) & 1u)) >> 16;  // RNE
  return (u16)r;
}

// async global->LDS, 16B per lane. LDS dest must be linear in lane order.
__device__ __forceinline__ void gload_lds16(const void* g, void* l) {
#if defined(__has_builtin)
#if __has_builtin(__builtin_amdgcn_global_load_lds)
  __builtin_amdgcn_global_load_lds((const __attribute__((address_space(1))) void*)g,
                                   (__attribute__((address_space(3))) void*)l, 16, 0, 0);
  return;
#endif
#endif
  *(uint4*)l = *(const uint4*)g;  // fallback
}

__device__ __forceinline__ u32 ld_relaxed(const u32* p) {
  return __hip_atomic_load(p, __ATOMIC_RELAXED, __HIP_MEMORY_SCOPE_AGENT);
}
__device__ __forceinline__ void acquire_fence_via(const u32* p) {
  u32 tmp = __hip_atomic_load(p, __ATOMIC_ACQUIRE, __HIP_MEMORY_SCOPE_AGENT);
  asm volatile("" :: "v"(tmp));  // keep the acquire load (emits cache inv)
}
__device__ __forceinline__ void st_release(u32* p, u32 v) {
  __hip_atomic_store(p, v, __ATOMIC_RELEASE, __HIP_MEMORY_SCOPE_AGENT);
}

// ---------------- f32 -> bf16 cast (weights) ----------------
__global__ void castk(const float* __restrict__ s, u16* __restrict__ d, int n4) {
  int i = blockIdx.x * blockDim.x + threadIdx.x;
  if (i < n4) {
    float4 v = ((const float4*)s)[i];
    ushort4 o;
    o.x = f2bf(v.x); o.y = f2bf(v.y); o.z = f2bf(v.z); o.w = f2bf(v.w);
    ((ushort4*)d)[i] = o;
  }
}

// cast into packed [W2|R2] rows: src (2048,512) f32 -> dst rows stride 1024, col offset dstOff
__global__ void cast2(const float* __restrict__ s, u16* __restrict__ d, int dstOff) {
  int i = blockIdx.x * blockDim.x + threadIdx.x;  // f32x4 chunks, 2048*128 total
  if (i < 2048 * 128) {
    int row = i >> 7, c4 = i & 127;
    float4 v = ((const float4*)s)[i];
    ushort4 o;
    o.x = f2bf(v.x); o.y = f2bf(v.y); o.z = f2bf(v.z); o.w = f2bf(v.w);
    ((ushort4*)(d + (size_t)row * 1024 + dstOff))[c4] = o;
  }
}

// ---------------- embed gather + add pos + cast, (S,B,768) bf16 ----------------
__global__ __launch_bounds__(192) void embed_k(const int* __restrict__ ids,
                                               const float* __restrict__ tok,
                                               const float* __restrict__ pos,
                                               u16* __restrict__ X) {
  const int row = blockIdx.x;          // row = t*256 + b
  const int t = row >> 8, b = row & 255;
  const int id = ids[b * SEQ_ + t];    // input_ids is (B,S)
  const float4* tr = (const float4*)(tok + (size_t)id * DIN_);
  const float4* pr = (const float4*)(pos + (size_t)t * DIN_);
  const int i = threadIdx.x;
  float4 v = tr[i], p = pr[i];
  ushort4 o;
  o.x = f2bf(v.x + p.x); o.y = f2bf(v.y + p.y);
  o.z = f2bf(v.z + p.z); o.w = f2bf(v.w + p.w);
  ((ushort4*)(X + (size_t)row * DIN_))[i] = o;
}

// ---------------- bf16 GEMM, C[m][n] = sum_k A[m][k]*B[n][k] + bias[n] ----------------
__global__ __launch_bounds__(256) void gemm_bt(const u16* __restrict__ A,
                                               const u16* __restrict__ Bm,
                                               const float* __restrict__ bias,
                                               u16* __restrict__ C,
                                               int M, int N, int K) {
  __shared__ __align__(16) u16 As[128 * 64];
  __shared__ __align__(16) u16 Bs[128 * 64];
  const int tid = threadIdx.x;
  const int lane = tid & 63;
  const int wave = tid >> 6;
  const int m0 = blockIdx.y * 128;
  const int n0 = blockIdx.x * 128;
  const int wm = (wave >> 1) * 64;
  const int wn = (wave & 1) * 64;
  const int lr = lane & 15;
  const int lg = lane >> 4;
  f32x4 acc[4][4] = {};

  for (int k0 = 0; k0 < K; k0 += 64) {
#pragma unroll
    for (int it = 0; it < 4; ++it) {
      int e = it * 256 + tid;
      int r = e >> 3, c8 = (e & 7) * 8;
      gload_lds16(A + (size_t)(m0 + r) * K + k0 + c8, &As[e * 8]);
      gload_lds16(Bm + (size_t)(n0 + r) * K + k0 + c8, &Bs[e * 8]);
    }
    __syncthreads();
#pragma unroll
    for (int kk = 0; kk < 64; kk += 32) {
      bf16x8 af[4], bfr[4];
#pragma unroll
      for (int i = 0; i < 4; ++i) {
        af[i]  = *(const bf16x8*)&As[(wm + i * 16 + lr) * 64 + kk + lg * 8];
        bfr[i] = *(const bf16x8*)&Bs[(wn + i * 16 + lr) * 64 + kk + lg * 8];
      }
#pragma unroll
      for (int i = 0; i < 4; ++i)
#pragma unroll
        for (int j = 0; j < 4; ++j)
          acc[i][j] = __builtin_amdgcn_mfma_f32_16x16x32_bf16(af[i], bfr[j], acc[i][j], 0, 0, 0);
    }
    __syncthreads();
  }
#pragma unroll
  for (int i = 0; i < 4; ++i) {
#pragma unroll
    for (int j = 0; j < 4; ++j) {
      int col = n0 + wn + j * 16 + lr;
      float bv = bias[col];
#pragma unroll
      for (int q = 0; q < 4; ++q) {
        int row = m0 + wm + i * 16 + lg * 4 + q;
        C[(size_t)row * N + col] = f2bf(acc[i][j][q] + bv);
      }
    }
  }
}

// ---------------- fused dual-chain wavefront recurrence ----------------
// 256 blocks (cooperative, 1/CU), 512 threads.
//   bid [0,128):   L1 — h1(t) = act(Xpre(t) + R1 h1(t-1)),     K=512
//   bid [128,256): L2 — h2(t) = act(W2 h1(t) + R2 h2(t-1) + b2), K=1024 fused [W2|R2]
// Tile: 64 batch rows (m4=lb&3) x 16 hid cols (j32=lb>>2), 4 gates.
// 8 waves = (gate = w&3, mhp = w>>2).
// h exchange protocol (R6 post-mortem: NT-load path ~1.7TB/s was the limiter):
//   producer: PLAIN cached h stores -> __syncthreads (per-wave vmcnt drain to L2)
//             -> tid0 RELEASE-store flag (compiler emits L2 writeback before flag).
//   consumer: relaxed poll -> ONE acquire load (emits cache inv) -> __syncthreads
//             -> PLAIN cached h loads (full-rate path, fresh post-inv).
// Weights pinned in VGPRs via asm "+v" each iteration (R6: compiler rematerialized
// them -> VGPR_Count 128; pin forces loop-carried residency).
__global__ __launch_bounds__(512, 2) void lstm_duo(
    const u16* __restrict__ Xpre,    // (S,256,2048) bf16, includes b1
    u16* __restrict__ H1,            // (S,256,512)
    u16* __restrict__ H2,            // (S,256,512)
    const u16* __restrict__ R1b,     // (2048,512)
    const u16* __restrict__ W2c,     // (2048,1024) = [W2|R2]
    const float* __restrict__ b2,    // (2048,)
    u32* __restrict__ flag1, u32* __restrict__ flag2) {
  __shared__ __align__(16) char lds[131072];   // As1 [0,64K), As2 [64K,128K)
  const int tid = threadIdx.x;
  const int lane = tid & 63;
  const int w = tid >> 6;
  const int lr = lane & 15, lg = lane >> 4;
  const int kind = blockIdx.x >> 7;            // 0=L1, 1=L2
  const int lb = blockIdx.x & 127;
  const int m4 = lb & 3, j32 = lb >> 2;
  const int m0 = m4 * 64, j0 = j32 * 16;
  const int gate = w & 3, mhp = w >> 2;
  const int cr = tid >> 3, cc = (tid & 7) * 2;
  float* Gsf = (float*)lds;                    // [4][64][17] f32 overlay on As1
  char* As2 = lds + 65536;

  if (kind == 0) {
    // =========================== L1 chain ===========================
    bf16x8 B1[16];
#pragma unroll
    for (int k = 0; k < 16; ++k)
      B1[k] = *(const bf16x8*)&R1b[(size_t)(gate * 512 + j0 + lr) * 512 + k * 32 + lg * 8];
    float cst0 = 0.f, cst1 = 0.f;

    for (int t = 0; t < SEQ_; ++t) {
      // pin weights in registers (prevents per-step rematerialization)
#pragma unroll
      for (int k = 0; k < 16; ++k) asm volatile("" : "+v"(B1[k]));
      // prefetch Xpre(t) (read-only phase-A data, plain loads)
      u32 xp[4];
#pragma unroll
      for (int g = 0; g < 4; ++g)
        xp[g] = *(const u32*)(Xpre + (size_t)t * (BATCH_ * NG_) +
                              (size_t)(m0 + cr) * NG_ + g * 512 + j0 + cc);
      if (t > 0) {
        if (w == 0) {  // poll sibling flags for h1(t-1), then one acquire (inv)
          const u32* f = flag1 + (size_t)(t - 1) * 128 + m4 * 32 + (lane & 31);
          int spins = 0;
          while (!__all(ld_relaxed(f) != 0)) {
            __builtin_amdgcn_s_sleep(1);
            if (++spins > (1 << 22)) break;
          }
          acquire_fence_via(f);
        }
        __syncthreads();   // all waves wait for inv before reading
        // stage h1(t-1) rows [m0,+64) -> As1, XOR-swizzled, PLAIN cached loads
        const u64* s64 = (const u64*)(H1 + (size_t)(t - 1) * (BATCH_ * HID_));
#pragma unroll
        for (int i = 0; i < 16; ++i) {
          int e = i * 512 + tid, r = e >> 7, c8 = e & 127;
          u64 v = s64[(size_t)(m0 + r) * 128 + c8];
          *(u64*)(lds + r * 1024 + ((((c8 >> 1) ^ (r & 7)) << 4) | ((c8 & 1) << 3))) = v;
        }
      }
      __syncthreads();
      f32x4 acc0 = {}, acc1 = {};
      if (t > 0) {
#pragma unroll
        for (int k = 0; k < 16; ++k) {
          int sw = (((k * 4 + lg) ^ (lr & 7)) << 4);
          bf16x8 a0 = *(const bf16x8*)(lds + (mhp * 32 + lr) * 1024 + sw);
          bf16x8 a1 = *(const bf16x8*)(lds + (mhp * 32 + 16 + lr) * 1024 + sw);
          acc0 = __builtin_amdgcn_mfma_f32_16x16x32_bf16(a0, B1[k], acc0, 0, 0, 0);
          acc1 = __builtin_amdgcn_mfma_f32_16x16x32_bf16(a1, B1[k], acc1, 0, 0, 0);
        }
      }
      __syncthreads();   // As1 reads done -> safe to overlay Gsf
#pragma unroll
      for (int q = 0; q < 4; ++q) {
        Gsf[gate * 1088 + (mhp * 32 + lg * 4 + q) * 17 + lr] = acc0[q];
        Gsf[gate * 1088 + (mhp * 32 + 16 + lg * 4 + q) * 17 + lr] = acc1[q];
      }
      __syncthreads();
      {  // cell update: thread owns (cr, cc..cc+1)
        float G[4][2];
#pragma unroll
        for (int g = 0; g < 4; ++g) {
          G[g][0] = Gsf[g * 1088 + cr * 17 + cc] + bf2f((u16)xp[g]);
          G[g][1] = Gsf[g * 1088 + cr * 17 + cc + 1] + bf2f((u16)(xp[g] >> 16));
        }
        u32 pack = 0;
        {
          float iv = 1.f / (1.f + expf(-G[0][0]));
          float fv = 1.f / (1.f + expf(-G[1][0]));
          float mv = tanhf(G[2][0]);
          float ov = 1.f / (1.f + expf(-G[3][0]));
          float cn = mv * iv + fv * cst0;
          cst0 = cn;
          pack |= (u32)f2bf(ov * tanhf(cn));
        }
        {
          float iv = 1.f / (1.f + expf(-G[0][1]));
          float fv = 1.f / (1.f + expf(-G[1][1]));
          float mv = tanhf(G[2][1]);
          float ov = 1.f / (1.f + expf(-G[3][1]));
          float cn = mv * iv + fv * cst1;
          cst1 = cn;
          pack |= (u32)f2bf(ov * tanhf(cn)) << 16;
        }
        *(u32*)(H1 + (size_t)t * (BATCH_ * HID_) +
                (size_t)(m0 + cr) * HID_ + j0 + cc) = pack;   // plain cached store
      }
      __syncthreads();   // each wave drains its stores to L2 before flag
      if (tid == 0)
        st_release(flag1 + (size_t)t * 128 + m4 * 32 + j32, 1u);  // wb L2 -> MALL, then flag
    }
  } else {
    // =========================== L2 chain ===========================
    bf16x8 B2[32];
#pragma unroll
    for (int k = 0; k < 32; ++k)
      B2[k] = *(const bf16x8*)&W2c[(size_t)(gate * 512 + j0 + lr) * 1024 + k * 32 + lg * 8];
    float bc[4][2];
#pragma unroll
    for (int g = 0; g < 4; ++g) {
      bc[g][0] = b2[g * 512 + j0 + cc];
      bc[g][1] = b2[g * 512 + j0 + cc + 1];
    }
    float cst0 = 0.f, cst1 = 0.f;

    for (int t = 0; t < SEQ_; ++t) {
#pragma unroll
      for (int k = 0; k < 32; ++k) asm volatile("" : "+v"(B2[k]));
      if (w == 0) {
        // lanes 0-31 poll flag1(t) [h1(t)]; lanes 32-63 poll flag2(t-1) [own chain]
        const u32* f1p = flag1 + (size_t)t * 128 + m4 * 32 + (lane & 31);
        const u32* f2p = flag2 + (size_t)(t > 0 ? t - 1 : 0) * 128 + m4 * 32 + (lane & 31);
        int spins = 0;
        while (true) {
          u32 v = (lane < 32) ? ld_relaxed(f1p) : ((t > 0) ? ld_relaxed(f2p) : 1u);
          if (__all(v != 0)) break;
          __builtin_amdgcn_s_sleep(1);
          if (++spins > (1 << 22)) break;
        }
        acquire_fence_via(f1p);   // one inv covers both h1 and h2 reads
      }
      __syncthreads();
      {  // stage As1 = h1(t), PLAIN cached loads
        const u64* s64 = (const u64*)(H1 + (size_t)t * (BATCH_ * HID_));
#pragma unroll
        for (int i = 0; i < 16; ++i) {
          int e = i * 512 + tid, r = e >> 7, c8 = e & 127;
          u64 v = s64[(size_t)(m0 + r) * 128 + c8];
          *(u64*)(lds + r * 1024 + ((((c8 >> 1) ^ (r & 7)) << 4) | ((c8 & 1) << 3))) = v;
        }
      }
      if (t > 0) {  // stage As2 = h2(t-1)
        const u64* s64 = (const u64*)(H2 + (size_t)(t - 1) * (BATCH_ * HID_));
#pragma unroll
        for (int i = 0; i < 16; ++i) {
          int e = i * 512 + tid, r = e >> 7, c8 = e & 127;
          u64 v = s64[(size_t)(m0 + r) * 128 + c8];
          *(u64*)(As2 + r * 1024 + ((((c8 >> 1) ^ (r & 7)) << 4) | ((c8 & 1) << 3))) = v;
        }
      }
      __syncthreads();
      f32x4 acc0 = {}, acc1 = {};
#pragma unroll
      for (int k = 0; k < 16; ++k) {   // W2 half (h1)
        int sw = (((k * 4 + lg) ^ (lr & 7)) << 4);
        bf16x8 a0 = *(const bf16x8*)(lds + (mhp * 32 + lr) * 1024 + sw);
        bf16x8 a1 = *(const bf16x8*)(lds + (mhp * 32 + 16 + lr) * 1024 + sw);
        acc0 = __builtin_amdgcn_mfma_f32_16x16x32_bf16(a0, B2[k], acc0, 0, 0, 0);
        acc1 = __builtin_amdgcn_mfma_f32_16x16x32_bf16(a1, B2[k], acc1, 0, 0, 0);
      }
      if (t > 0) {
#pragma unroll
        for (int k = 0; k < 16; ++k) {  // R2 half (h2)
          int sw = (((k * 4 + lg) ^ (lr & 7)) << 4);
          bf16x8 a0 = *(const bf16x8*)(As2 + (mhp * 32 + lr) * 1024 + sw);
          bf16x8 a1 = *(const bf16x8*)(As2 + (mhp * 32 + 16 + lr) * 1024 + sw);
          acc0 = __builtin_amdgcn_mfma_f32_16x16x32_bf16(a0, B2[16 + k], acc0, 0, 0, 0);
          acc1 = __builtin_amdgcn_mfma_f32_16x16x32_bf16(a1, B2[16 + k], acc1, 0, 0, 0);
        }
      }
      __syncthreads();
#pragma unroll
      for (int q = 0; q < 4; ++q) {
        Gsf[gate * 1088 + (mhp * 32 + lg * 4 + q) * 17 + lr] = acc0[q];
        Gsf[gate * 1088 + (mhp * 32 + 16 + lg * 4 + q) * 17 + lr] = acc1[q];
      }
      __syncthreads();
      {
        float G[4][2];
#pragma unroll
        for (int g = 0; g < 4; ++g) {
          G[g][0] = Gsf[g * 1088 + cr * 17 + cc] + bc[g][0];
          G[g][1] = Gsf[g * 1088 + cr * 17 + cc + 1] + bc[g][1];
        }
        u32 pack = 0;
        {
          float iv = 1.f / (1.f + expf(-G[0][0]));
          float fv = 1.f / (1.f + expf(-G[1][0]));
          float mv = tanhf(G[2][0]);
          float ov = 1.f / (1.f + expf(-G[3][0]));
          float cn = mv * iv + fv * cst0;
          cst0 = cn;
          pack |= (u32)f2bf(ov * tanhf(cn));
        }
        {
          float iv = 1.f / (1.f + expf(-G[0][1]));
          float fv = 1.f / (1.f + expf(-G[1][1]));
          float mv = tanhf(G[2][1]);
          float ov = 1.f / (1.f + expf(-G[3][1]));
          float cn = mv * iv + fv * cst1;
          cst1 = cn;
          pack |= (u32)f2bf(ov * tanhf(cn)) << 16;
        }
        *(u32*)(H2 + (size_t)t * (BATCH_ * HID_) +
                (size_t)(m0 + cr) * HID_ + j0 + cc) = pack;   // plain cached store
      }
      __syncthreads();
      if (tid == 0)
        st_release(flag2 + (size_t)t * 128 + m4 * 32 + j32, 1u);
    }
  }
}

// ---------------- output projection: out[b][t][cls] = h2 . Wo[cls] + bo ----------------
__global__ __launch_bounds__(320) void out_proj(const u16* __restrict__ H2,
                                                const float* __restrict__ Wo,
                                                const float* __restrict__ bo,
                                                float* __restrict__ out) {
  __shared__ __align__(16) u16 Hs[32 * 520];
  const int r0 = blockIdx.x * 32;     // flat row = t*256 + b
  const int tid = threadIdx.x;
  for (int e = tid; e < 2048; e += 320) {
    int rl = e >> 6, k8 = (e & 63) * 8;
    *(uint4*)&Hs[rl * 520 + k8] = *(const uint4*)(H2 + (size_t)(r0 + rl) * HID_ + k8);
  }
  __syncthreads();
  if (tid < 288) {
    int rl = tid / 9, cls = tid - rl * 9;
    const u16* h = &Hs[rl * 520];
    const float* wv = Wo + cls * HID_;
    float s = bo[cls];
#pragma unroll 8
    for (int k = 0; k < HID_; ++k) s += bf2f(h[k]) * wv[k];
    int r = r0 + rl, t = r >> 8, b = r & 255;
    out[((size_t)b * SEQ_ + t) * NCLS_ + cls] = s;
  }
}

extern "C" void kernel_launch(void* const* d_in, const int* in_sizes, int n_in,
                              void* d_out, int out_size, void* d_ws, size_t ws_size,
                              hipStream_t stream) {
  (void)in_sizes; (void)n_in; (void)out_size; (void)ws_size;
  const int*   ids = (const int*)d_in[0];
  const float* tok = (const float*)d_in[1];
  const float* pos = (const float*)d_in[2];
  const float* W1  = (const float*)d_in[3];
  const float* R1  = (const float*)d_in[4];
  const float* b1  = (const float*)d_in[5];
  const float* W2  = (const float*)d_in[6];
  const float* R2  = (const float*)d_in[7];
  const float* b2  = (const float*)d_in[8];
  const float* Wo  = (const float*)d_in[9];
  const float* bo  = (const float*)d_in[10];
  float* out = (float*)d_out;

  // workspace (~226 MB); H1all overlays Xbf (dead after phase A)
  char* p = (char*)d_ws;
  auto alloc = [&](size_t bytes) { char* q = p; p += (bytes + 255) & ~(size_t)255; return q; };
  u16*  W1b  = (u16*)alloc((size_t)NG_ * DIN_ * 2);                 // 3MB
  u16*  R1b  = (u16*)alloc((size_t)NG_ * HID_ * 2);                 // 2MB
  u16*  W2c  = (u16*)alloc((size_t)NG_ * 1024 * 2);                 // 4MB [W2|R2]
  u32*  flag1 = (u32*)alloc((size_t)SEQ_ * 128 * 4);                // 64KB
  u32*  flag2 = (u32*)alloc((size_t)SEQ_ * 128 * 4);                // 64KB
  size_t xbf_bytes = (size_t)SEQ_ * BATCH_ * DIN_ * 2;              // 50.3MB
  u16*  Xbf  = (u16*)alloc(xbf_bytes);
  u16*  H1all = Xbf;                                                // overlay (32MB < 50.3MB)
  u16*  H2all = (u16*)alloc((size_t)SEQ_ * BATCH_ * HID_ * 2);      // 32MB
  u16*  Xpre = (u16*)alloc((size_t)SEQ_ * BATCH_ * NG_ * 2);        // 134MB

  // weight casts
  castk<<<dim3((NG_ * DIN_ / 4 + 255) / 256), 256, 0, stream>>>(W1, W1b, NG_ * DIN_ / 4);
  castk<<<dim3((NG_ * HID_ / 4 + 255) / 256), 256, 0, stream>>>(R1, R1b, NG_ * HID_ / 4);
  cast2<<<dim3(1024), 256, 0, stream>>>(W2, W2c, 0);
  cast2<<<dim3(1024), 256, 0, stream>>>(R2, W2c, 512);
  // flags must be zero each call (graph replays re-run this memset)
  hipMemsetAsync(flag1, 0, (size_t)SEQ_ * 256 * 4, stream);  // flag1+flag2 contiguous

  // embeds -> (S,B,768) bf16
  embed_k<<<dim3(SEQ_ * BATCH_), 192, 0, stream>>>(ids, tok, pos, Xbf);

  // phase A: Xpre = X @ W1^T + b1   (32768 x 2048, K=768)
  gemm_bt<<<dim3(NG_ / 128, SEQ_ * BATCH_ / 128), 256, 0, stream>>>(
      Xbf, W1b, b1, Xpre, SEQ_ * BATCH_, NG_, DIN_);

  // fused dual-chain recurrence (cooperative: co-residency for spin-wait)
  {
    const u16* Xp = Xpre; u16* H1a = H1all; u16* H2a = H2all;
    const u16* R1a = R1b; const u16* W2a = W2c; const float* b2a = b2;
    u32* f1 = flag1; u32* f2 = flag2;
    void* args[] = {(void*)&Xp, (void*)&H1a, (void*)&H2a, (void*)&R1a,
                    (void*)&W2a, (void*)&b2a, (void*)&f1, (void*)&f2};
    hipLaunchCooperativeKernel(reinterpret_cast<void*>(&lstm_duo),
                               dim3(256), dim3(512), args, 0, stream);
  }

  // logits
  out_proj<<<dim3(SEQ_ * BATCH_ / 32), 320, 0, stream>>>(H2all, Wo, bo, out);
}

// Round 9
// 2140.846 us; speedup vs baseline: 1.2090x; 1.2090x over previous
//
#include <hip/hip_runtime.h>
#include <hip/hip_bf16.h>
#include <stdint.h>

// Problem constants
#define BATCH_ 256
#define SEQ_   128
#define DIN_   768
#define HID_   512
#define NG_    2048   // 4*HID
#define NCLS_  9

typedef unsigned short u16;
typedef unsigned int u32;
typedef unsigned long long u64;
typedef __attribute__((ext_vector_type(8))) short bf16x8;
typedef __attribute__((ext_vector_type(4))) float f32x4;

__device__ __forceinline__ float bf2f(u16 u) {
  return __builtin_bit_cast(float, (uint32_t)u << 16);
}
__device__ __forceinline__ u16 f2bf(float f) {
  uint32_t x = __builtin_bit_cast(uint32_t, f);
  uint32_t r = (x + 0x7fffu + ((x >> 16) & 1u)) >> 16;  // RNE
  return (u16)r;
}

// async global->LDS, 16B per lane (gemm_bt staging only)
__device__ __forceinline__ void gload_lds16(const void* g, void* l) {
#if defined(__has_builtin)
#if __has_builtin(__builtin_amdgcn_global_load_lds)
  __builtin_amdgcn_global_load_lds((const __attribute__((address_space(1))) void*)g,
                                   (__attribute__((address_space(3))) void*)l, 16, 0, 0);
  return;
#endif
#endif
  *(uint4*)l = *(const uint4*)g;  // fallback
}

__device__ __forceinline__ u32 aload32(const u32* p) {
  return __hip_atomic_load(p, __ATOMIC_RELAXED, __HIP_MEMORY_SCOPE_AGENT);
}
__device__ __forceinline__ u64 aload64(const u64* p) {
  return __hip_atomic_load(p, __ATOMIC_RELAXED, __HIP_MEMORY_SCOPE_AGENT);
}
__device__ __forceinline__ void astore32(u32* p, u32 v) {
  __hip_atomic_store(p, v, __ATOMIC_RELAXED, __HIP_MEMORY_SCOPE_AGENT);
}
__device__ __forceinline__ void astore32_rel(u32* p, u32 v) {
  __hip_atomic_store(p, v, __ATOMIC_RELEASE, __HIP_MEMORY_SCOPE_AGENT);
}

// ---------------- f32 -> bf16 cast (weights) ----------------
__global__ void castk(const float* __restrict__ s, u16* __restrict__ d, int n4) {
  int i = blockIdx.x * blockDim.x + threadIdx.x;
  if (i < n4) {
    float4 v = ((const float4*)s)[i];
    ushort4 o;
    o.x = f2bf(v.x); o.y = f2bf(v.y); o.z = f2bf(v.z); o.w = f2bf(v.w);
    ((ushort4*)d)[i] = o;
  }
}

// ---------------- embed gather + add pos + cast, (S,B,768) bf16 ----------------
__global__ __launch_bounds__(192) void embed_k(const int* __restrict__ ids,
                                               const float* __restrict__ tok,
                                               const float* __restrict__ pos,
                                               u16* __restrict__ X) {
  const int row = blockIdx.x;          // row = t*256 + b
  const int t = row >> 8, b = row & 255;
  const int id = ids[b * SEQ_ + t];    // input_ids is (B,S)
  const float4* tr = (const float4*)(tok + (size_t)id * DIN_);
  const float4* pr = (const float4*)(pos + (size_t)t * DIN_);
  const int i = threadIdx.x;
  float4 v = tr[i], p = pr[i];
  ushort4 o;
  o.x = f2bf(v.x + p.x); o.y = f2bf(v.y + p.y);
  o.z = f2bf(v.z + p.z); o.w = f2bf(v.w + p.w);
  ((ushort4*)(X + (size_t)row * DIN_))[i] = o;
}

// ---------------- bf16 GEMM, C[m][n] = sum_k A[m][k]*B[n][k] + bias[n] ----------------
__global__ __launch_bounds__(256) void gemm_bt(const u16* __restrict__ A,
                                               const u16* __restrict__ Bm,
                                               const float* __restrict__ bias,
                                               u16* __restrict__ C,
                                               int M, int N, int K) {
  __shared__ __align__(16) u16 As[128 * 64];
  __shared__ __align__(16) u16 Bs[128 * 64];
  const int tid = threadIdx.x;
  const int lane = tid & 63;
  const int wave = tid >> 6;
  const int m0 = blockIdx.y * 128;
  const int n0 = blockIdx.x * 128;
  const int wm = (wave >> 1) * 64;
  const int wn = (wave & 1) * 64;
  const int lr = lane & 15;
  const int lg = lane >> 4;
  f32x4 acc[4][4] = {};

  for (int k0 = 0; k0 < K; k0 += 64) {
#pragma unroll
    for (int it = 0; it < 4; ++it) {
      int e = it * 256 + tid;
      int r = e >> 3, c8 = (e & 7) * 8;
      gload_lds16(A + (size_t)(m0 + r) * K + k0 + c8, &As[e * 8]);
      gload_lds16(Bm + (size_t)(n0 + r) * K + k0 + c8, &Bs[e * 8]);
    }
    __syncthreads();
#pragma unroll
    for (int kk = 0; kk < 64; kk += 32) {
      bf16x8 af[4], bfr[4];
#pragma unroll
      for (int i = 0; i < 4; ++i) {
        af[i]  = *(const bf16x8*)&As[(wm + i * 16 + lr) * 64 + kk + lg * 8];
        bfr[i] = *(const bf16x8*)&Bs[(wn + i * 16 + lr) * 64 + kk + lg * 8];
      }
#pragma unroll
      for (int i = 0; i < 4; ++i)
#pragma unroll
        for (int j = 0; j < 4; ++j)
          acc[i][j] = __builtin_amdgcn_mfma_f32_16x16x32_bf16(af[i], bfr[j], acc[i][j], 0, 0, 0);
    }
    __syncthreads();
  }
#pragma unroll
  for (int i = 0; i < 4; ++i) {
#pragma unroll
    for (int j = 0; j < 4; ++j) {
      int col = n0 + wn + j * 16 + lr;
      float bv = bias[col];
#pragma unroll
      for (int q = 0; q < 4; ++q) {
        int row = m0 + wm + i * 16 + lg * 4 + q;
        C[(size_t)row * N + col] = f2bf(acc[i][j][q] + bv);
      }
    }
  }
}

// stage 64 rows x 512 cols bf16 (row stride 512) into LDS, XOR-swizzled, via
// agent-scope atomic loads (MALL-coherent; R4/R6-proven path).
__device__ __forceinline__ void stage64(char* dst, const u16* src, int tid) {
  const u64* s64 = (const u64*)src;
#pragma unroll
  for (int i = 0; i < 16; ++i) {
    int e = i * 512 + tid, r = e >> 7, c8 = e & 127;
    u64 v = aload64(&s64[(size_t)r * 128 + c8]);
    *(u64*)(dst + r * 1024 + ((((c8 >> 1) ^ (r & 7)) << 4) | ((c8 & 1) << 3))) = v;
  }
}

// ---------------- fused dual-chain wavefront recurrence, v2 ----------------
// 256 blocks (cooperative, 1/CU via 128KB LDS), 512 threads.
//   bid [0,128):   L1 — h1(t) = act(Xpre(t) + R1 h1(t-1)),        K=512
//   bid [128,256): L2 — h2(t) = act(W2 h1(t) + R2 h2(t-1) + b2),  K=512+512
// Tile: 64 batch rows (m4) x 16 hid cols (j32), 4 gates. 128 blocks per layer.
// 8 waves = (gate = w&3, K-half kh = w>>2): per-wave weights L1 8 frags (32 VGPR),
// L2 8+8 frags (64 VGPR) — small enough that the compiler holds them register-
// resident (R6/R7 pathology: 2x-duplicated weights + 128-VGPR cap -> per-step
// reloads). K-half partial gate sums combined via Gs[2] (R4-proven).
// L2 CRITICAL-PATH FIX vs R6: do the R2·h2(t-1) half FIRST (flag2(t-1) is old),
// poll flag1(t) only afterwards — L2's post-flag1 tail is ~2µs, so the fused
// pipeline advances at the L1 chain's own cadence instead of L1+L2 serialized.
// Cross-block protocol verbatim R4/R6 (passed 3x): relaxed agent atomics for h,
// __syncthreads vmcnt-drain, release flag store, bounded spins.
__global__ __launch_bounds__(512, 2) void lstm_duo2(
    const u16* __restrict__ Xpre,    // (S,256,2048) bf16, includes b1
    u16* __restrict__ H1,            // (S,256,512)
    u16* __restrict__ H2,            // (S,256,512)
    const u16* __restrict__ R1b,     // (2048,512)
    const u16* __restrict__ W2b,     // (2048,512)
    const u16* __restrict__ R2b,     // (2048,512)
    const float* __restrict__ b2,    // (2048,)
    u32* __restrict__ flag1, u32* __restrict__ flag2) {
  __shared__ __align__(16) char lds[131072];   // As1 [0,64K) | As2 [64K,128K)
  const int tid = threadIdx.x;
  const int lane = tid & 63;
  const int w = tid >> 6;
  const int lr = lane & 15, lg = lane >> 4;
  const int kind = blockIdx.x >> 7;            // 0=L1, 1=L2
  const int lb = blockIdx.x & 127;
  const int m4 = lb & 3, j32 = lb >> 2;
  const int m0 = m4 * 64, j0 = j32 * 16;
  const int g = w & 3, kh = w >> 2;            // wave = (gate, K-half)
  const int cr = tid >> 3, cc = (tid & 7) * 2; // epilogue cell ownership
  float* Gsf = (float*)lds;                    // [2][4][64][17] f32 overlay on As1
  char* As1 = lds;
  char* As2 = lds + 65536;

#define GS(KH, GG, RR, CC) Gsf[(((KH) * 4 + (GG)) * 64 + (RR)) * 17 + (CC)]

  if (kind == 0) {
    // =========================== L1 chain ===========================
    bf16x8 B1[8];
#pragma unroll
    for (int k = 0; k < 8; ++k)
      B1[k] = *(const bf16x8*)&R1b[(size_t)(g * 512 + j0 + lr) * 512 +
                                   kh * 256 + k * 32 + lg * 8];
    float cst0 = 0.f, cst1 = 0.f;

    for (int t = 0; t < SEQ_; ++t) {
      // prefetch Xpre(t) (read-only phase-A data, plain loads)
      u32 xp[4];
#pragma unroll
      for (int gg = 0; gg < 4; ++gg)
        xp[gg] = *(const u32*)(Xpre + (size_t)t * (BATCH_ * NG_) +
                               (size_t)(m0 + cr) * NG_ + gg * 512 + j0 + cc);
      if (t > 0) {
        if (w == 0) {   // poll own rg's 32 sibling flags for h1(t-1)
          const u32* f = flag1 + (size_t)(t - 1) * 128 + m4 * 32 + (lane & 31);
          int spins = 0;
          while (!__all(aload32(f) != 0)) {
            __builtin_amdgcn_s_sleep(1);
            if (++spins > (1 << 20)) break;
          }
        }
        __syncthreads();
        stage64(As1, H1 + ((size_t)(t - 1) * BATCH_ + m0) * HID_, tid);
      }
      __syncthreads();
      f32x4 acc[4] = {};
      if (t > 0) {
#pragma unroll
        for (int rf = 0; rf < 4; ++rf) {
#pragma unroll
          for (int k = 0; k < 8; ++k) {
            int c = kh * 32 + k * 4 + lg;
            bf16x8 a = *(const bf16x8*)(As1 + (rf * 16 + lr) * 1024 +
                                        ((c ^ (lr & 7)) << 4));
            acc[rf] = __builtin_amdgcn_mfma_f32_16x16x32_bf16(a, B1[k], acc[rf], 0, 0, 0);
          }
        }
      }
      __syncthreads();   // As1 reads done -> Gs overlay safe
#pragma unroll
      for (int rf = 0; rf < 4; ++rf)
#pragma unroll
        for (int q = 0; q < 4; ++q)
          GS(kh, g, rf * 16 + lg * 4 + q, lr) = acc[rf][q];
      __syncthreads();
      {  // cell update: thread owns (cr, cc..cc+1)
        float G[4][2];
#pragma unroll
        for (int gg = 0; gg < 4; ++gg) {
          G[gg][0] = GS(0, gg, cr, cc) + GS(1, gg, cr, cc) + bf2f((u16)xp[gg]);
          G[gg][1] = GS(0, gg, cr, cc + 1) + GS(1, gg, cr, cc + 1) + bf2f((u16)(xp[gg] >> 16));
        }
        u32 pack = 0;
        {
          float iv = 1.f / (1.f + expf(-G[0][0]));
          float fv = 1.f / (1.f + expf(-G[1][0]));
          float mv = tanhf(G[2][0]);
          float ov = 1.f / (1.f + expf(-G[3][0]));
          float cn = mv * iv + fv * cst0; cst0 = cn;
          pack |= (u32)f2bf(ov * tanhf(cn));
        }
        {
          float iv = 1.f / (1.f + expf(-G[0][1]));
          float fv = 1.f / (1.f + expf(-G[1][1]));
          float mv = tanhf(G[2][1]);
          float ov = 1.f / (1.f + expf(-G[3][1]));
          float cn = mv * iv + fv * cst1; cst1 = cn;
          pack |= (u32)f2bf(ov * tanhf(cn)) << 16;
        }
        astore32((u32*)(H1 + (size_t)t * (BATCH_ * HID_) +
                        (size_t)(m0 + cr) * HID_ + j0 + cc), pack);
      }
      __syncthreads();   // vmcnt(0) drain: h stores visible before flag
      if (tid == 0)
        astore32_rel(flag1 + (size_t)t * 128 + m4 * 32 + j32, 1u);
    }
  } else {
    // =========================== L2 chain ===========================
    bf16x8 W2f[8], R2f[8];
#pragma unroll
    for (int k = 0; k < 8; ++k) {
      size_t off = (size_t)(g * 512 + j0 + lr) * 512 + kh * 256 + k * 32 + lg * 8;
      W2f[k] = *(const bf16x8*)&W2b[off];
      R2f[k] = *(const bf16x8*)&R2b[off];
    }
    float bc[4][2];
#pragma unroll
    for (int gg = 0; gg < 4; ++gg) {
      bc[gg][0] = b2[gg * 512 + j0 + cc];
      bc[gg][1] = b2[gg * 512 + j0 + cc + 1];
    }
    float cst0 = 0.f, cst1 = 0.f;

    for (int t = 0; t < SEQ_; ++t) {
      f32x4 acc[4] = {};
      // ---- phase 1: R2 . h2(t-1) — own-chain flag is old, near-zero wait ----
      if (t > 0) {
        if (w == 0) {
          const u32* f = flag2 + (size_t)(t - 1) * 128 + m4 * 32 + (lane & 31);
          int spins = 0;
          while (!__all(aload32(f) != 0)) {
            __builtin_amdgcn_s_sleep(1);
            if (++spins > (1 << 20)) break;
          }
        }
        __syncthreads();
        stage64(As2, H2 + ((size_t)(t - 1) * BATCH_ + m0) * HID_, tid);
        __syncthreads();
#pragma unroll
        for (int rf = 0; rf < 4; ++rf) {
#pragma unroll
          for (int k = 0; k < 8; ++k) {
            int c = kh * 32 + k * 4 + lg;
            bf16x8 a = *(const bf16x8*)(As2 + (rf * 16 + lr) * 1024 +
                                        ((c ^ (lr & 7)) << 4));
            acc[rf] = __builtin_amdgcn_mfma_f32_16x16x32_bf16(a, R2f[k], acc[rf], 0, 0, 0);
          }
        }
      }
      // ---- phase 2: W2 . h1(t) — poll L1's flag only now ----
      if (w == 0) {
        const u32* f = flag1 + (size_t)t * 128 + m4 * 32 + (lane & 31);
        int spins = 0;
        while (!__all(aload32(f) != 0)) {
          __builtin_amdgcn_s_sleep(1);
          if (++spins > (1 << 20)) break;
        }
      }
      __syncthreads();
      stage64(As1, H1 + ((size_t)t * BATCH_ + m0) * HID_, tid);  // overwrites old Gs (dead)
      __syncthreads();
#pragma unroll
      for (int rf = 0; rf < 4; ++rf) {
#pragma unroll
        for (int k = 0; k < 8; ++k) {
          int c = kh * 32 + k * 4 + lg;
          bf16x8 a = *(const bf16x8*)(As1 + (rf * 16 + lr) * 1024 +
                                      ((c ^ (lr & 7)) << 4));
          acc[rf] = __builtin_amdgcn_mfma_f32_16x16x32_bf16(a, W2f[k], acc[rf], 0, 0, 0);
        }
      }
      __syncthreads();   // As1 reads done -> Gs overlay safe
#pragma unroll
      for (int rf = 0; rf < 4; ++rf)
#pragma unroll
        for (int q = 0; q < 4; ++q)
          GS(kh, g, rf * 16 + lg * 4 + q, lr) = acc[rf][q];
      __syncthreads();
      {
        float G[4][2];
#pragma unroll
        for (int gg = 0; gg < 4; ++gg) {
          G[gg][0] = GS(0, gg, cr, cc) + GS(1, gg, cr, cc) + bc[gg][0];
          G[gg][1] = GS(0, gg, cr, cc + 1) + GS(1, gg, cr, cc + 1) + bc[gg][1];
        }
        u32 pack = 0;
        {
          float iv = 1.f / (1.f + expf(-G[0][0]));
          float fv = 1.f / (1.f + expf(-G[1][0]));
          float mv = tanhf(G[2][0]);
          float ov = 1.f / (1.f + expf(-G[3][0]));
          float cn = mv * iv + fv * cst0; cst0 = cn;
          pack |= (u32)f2bf(ov * tanhf(cn));
        }
        {
          float iv = 1.f / (1.f + expf(-G[0][1]));
          float fv = 1.f / (1.f + expf(-G[1][1]));
          float mv = tanhf(G[2][1]);
          float ov = 1.f / (1.f + expf(-G[3][1]));
          float cn = mv * iv + fv * cst1; cst1 = cn;
          pack |= (u32)f2bf(ov * tanhf(cn)) << 16;
        }
        astore32((u32*)(H2 + (size_t)t * (BATCH_ * HID_) +
                        (size_t)(m0 + cr) * HID_ + j0 + cc), pack);
      }
      __syncthreads();
      if (tid == 0)
        astore32_rel(flag2 + (size_t)t * 128 + m4 * 32 + j32, 1u);
    }
  }
#undef GS
}

// ---------------- output projection: out[b][t][cls] = h2 . Wo[cls] + bo ----------------
__global__ __launch_bounds__(320) void out_proj(const u16* __restrict__ H2,
                                                const float* __restrict__ Wo,
                                                const float* __restrict__ bo,
                                                float* __restrict__ out) {
  __shared__ __align__(16) u16 Hs[32 * 520];
  const int r0 = blockIdx.x * 32;     // flat row = t*256 + b
  const int tid = threadIdx.x;
  for (int e = tid; e < 2048; e += 320) {
    int rl = e >> 6, k8 = (e & 63) * 8;
    *(uint4*)&Hs[rl * 520 + k8] = *(const uint4*)(H2 + (size_t)(r0 + rl) * HID_ + k8);
  }
  __syncthreads();
  if (tid < 288) {
    int rl = tid / 9, cls = tid - rl * 9;
    const u16* h = &Hs[rl * 520];
    const float* wv = Wo + cls * HID_;
    float s = bo[cls];
#pragma unroll 8
    for (int k = 0; k < HID_; ++k) s += bf2f(h[k]) * wv[k];
    int r = r0 + rl, t = r >> 8, b = r & 255;
    out[((size_t)b * SEQ_ + t) * NCLS_ + cls] = s;
  }
}

extern "C" void kernel_launch(void* const* d_in, const int* in_sizes, int n_in,
                              void* d_out, int out_size, void* d_ws, size_t ws_size,
                              hipStream_t stream) {
  (void)in_sizes; (void)n_in; (void)out_size; (void)ws_size;
  const int*   ids = (const int*)d_in[0];
  const float* tok = (const float*)d_in[1];
  const float* pos = (const float*)d_in[2];
  const float* W1  = (const float*)d_in[3];
  const float* R1  = (const float*)d_in[4];
  const float* b1  = (const float*)d_in[5];
  const float* W2  = (const float*)d_in[6];
  const float* R2  = (const float*)d_in[7];
  const float* b2  = (const float*)d_in[8];
  const float* Wo  = (const float*)d_in[9];
  const float* bo  = (const float*)d_in[10];
  float* out = (float*)d_out;

  // workspace (~226 MB); H1all overlays Xbf (dead after phase A)
  char* p = (char*)d_ws;
  auto alloc = [&](size_t bytes) { char* q = p; p += (bytes + 255) & ~(size_t)255; return q; };
  u16*  W1b  = (u16*)alloc((size_t)NG_ * DIN_ * 2);                 // 3MB
  u16*  R1b  = (u16*)alloc((size_t)NG_ * HID_ * 2);                 // 2MB
  u16*  W2b  = (u16*)alloc((size_t)NG_ * HID_ * 2);                 // 2MB
  u16*  R2b  = (u16*)alloc((size_t)NG_ * HID_ * 2);                 // 2MB
  u32*  flag1 = (u32*)alloc((size_t)SEQ_ * 128 * 4);                // 64KB
  u32*  flag2 = (u32*)alloc((size_t)SEQ_ * 128 * 4);                // 64KB
  size_t xbf_bytes = (size_t)SEQ_ * BATCH_ * DIN_ * 2;              // 50.3MB
  u16*  Xbf  = (u16*)alloc(xbf_bytes);
  u16*  H1all = Xbf;                                                // overlay (32MB < 50.3MB)
  u16*  H2all = (u16*)alloc((size_t)SEQ_ * BATCH_ * HID_ * 2);      // 32MB
  u16*  Xpre = (u16*)alloc((size_t)SEQ_ * BATCH_ * NG_ * 2);        // 134MB

  // weight casts
  castk<<<dim3((NG_ * DIN_ / 4 + 255) / 256), 256, 0, stream>>>(W1, W1b, NG_ * DIN_ / 4);
  castk<<<dim3((NG_ * HID_ / 4 + 255) / 256), 256, 0, stream>>>(R1, R1b, NG_ * HID_ / 4);
  castk<<<dim3((NG_ * HID_ / 4 + 255) / 256), 256, 0, stream>>>(W2, W2b, NG_ * HID_ / 4);
  castk<<<dim3((NG_ * HID_ / 4 + 255) / 256), 256, 0, stream>>>(R2, R2b, NG_ * HID_ / 4);
  // flags must be zero each call (graph replays re-run this memset)
  hipMemsetAsync(flag1, 0, (size_t)SEQ_ * 256 * 4, stream);  // flag1+flag2 contiguous

  // embeds -> (S,B,768) bf16
  embed_k<<<dim3(SEQ_ * BATCH_), 192, 0, stream>>>(ids, tok, pos, Xbf);

  // phase A: Xpre = X @ W1^T + b1   (32768 x 2048, K=768)
  gemm_bt<<<dim3(NG_ / 128, SEQ_ * BATCH_ / 128), 256, 0, stream>>>(
      Xbf, W1b, b1, Xpre, SEQ_ * BATCH_, NG_, DIN_);

  // fused dual-chain recurrence (cooperative: co-residency for spin-wait)
  {
    const u16* Xp = Xpre; u16* H1a = H1all; u16* H2a = H2all;
    const u16* R1a = R1b; const u16* W2a = W2b; const u16* R2a = R2b;
    const float* b2a = b2;
    u32* f1 = flag1; u32* f2 = flag2;
    void* args[] = {(void*)&Xp, (void*)&H1a, (void*)&H2a, (void*)&R1a,
                    (void*)&W2a, (void*)&R2a, (void*)&b2a, (void*)&f1, (void*)&f2};
    hipLaunchCooperativeKernel(reinterpret_cast<void*>(&lstm_duo2),
                               dim3(256), dim3(512), args, 0, stream);
  }

  // logits
  out_proj<<<dim3(SEQ_ * BATCH_ / 32), 320, 0, stream>>>(H2all, Wo, bo, out);
}

// Round 10
// 1534.913 us; speedup vs baseline: 1.6862x; 1.3948x over previous
//
#include <hip/hip_runtime.h>
#include <hip/hip_bf16.h>
#include <stdint.h>

// Problem constants
#define BATCH_ 256
#define SEQ_   128
#define DIN_   768
#define HID_   512
#define NG_    2048   // 4*HID
#define NCLS_  9

typedef unsigned short u16;
typedef unsigned int u32;
typedef unsigned long long u64;
typedef __attribute__((ext_vector_type(8))) short bf16x8;
typedef __attribute__((ext_vector_type(4))) float f32x4;

__device__ __forceinline__ float bf2f(u16 u) {
  return __builtin_bit_cast(float, (uint32_t)u << 16);
}
__device__ __forceinline__ u16 f2bf(float f) {
  uint32_t x = __builtin_bit_cast(uint32_t, f);
  uint32_t r = (x + 0x7fffu + ((x >> 16) & 1u)) >> 16;  // RNE
  return (u16)r;
}

// async global->LDS, 16B per lane (gemm_bt staging only)
__device__ __forceinline__ void gload_lds16(const void* g, void* l) {
#if defined(__has_builtin)
#if __has_builtin(__builtin_amdgcn_global_load_lds)
  __builtin_amdgcn_global_load_lds((const __attribute__((address_space(1))) void*)g,
                                   (__attribute__((address_space(3))) void*)l, 16, 0, 0);
  return;
#endif
#endif
  *(uint4*)l = *(const uint4*)g;  // fallback
}

__device__ __forceinline__ u32 aload32(const u32* p) {
  return __hip_atomic_load(p, __ATOMIC_RELAXED, __HIP_MEMORY_SCOPE_AGENT);
}
__device__ __forceinline__ void astore32(u32* p, u32 v) {
  __hip_atomic_store(p, v, __ATOMIC_RELAXED, __HIP_MEMORY_SCOPE_AGENT);
}
__device__ __forceinline__ void astore32_rel(u32* p, u32 v) {
  __hip_atomic_store(p, v, __ATOMIC_RELEASE, __HIP_MEMORY_SCOPE_AGENT);
}

// ---------------- f32 -> bf16 cast (weights) ----------------
__global__ void castk(const float* __restrict__ s, u16* __restrict__ d, int n4) {
  int i = blockIdx.x * blockDim.x + threadIdx.x;
  if (i < n4) {
    float4 v = ((const float4*)s)[i];
    ushort4 o;
    o.x = f2bf(v.x); o.y = f2bf(v.y); o.z = f2bf(v.z); o.w = f2bf(v.w);
    ((ushort4*)d)[i] = o;
  }
}

// ---------------- embed gather + add pos + cast, (S,B,768) bf16 ----------------
__global__ __launch_bounds__(192) void embed_k(const int* __restrict__ ids,
                                               const float* __restrict__ tok,
                                               const float* __restrict__ pos,
                                               u16* __restrict__ X) {
  const int row = blockIdx.x;          // row = t*256 + b
  const int t = row >> 8, b = row & 255;
  const int id = ids[b * SEQ_ + t];    // input_ids is (B,S)
  const float4* tr = (const float4*)(tok + (size_t)id * DIN_);
  const float4* pr = (const float4*)(pos + (size_t)t * DIN_);
  const int i = threadIdx.x;
  float4 v = tr[i], p = pr[i];
  ushort4 o;
  o.x = f2bf(v.x + p.x); o.y = f2bf(v.y + p.y);
  o.z = f2bf(v.z + p.z); o.w = f2bf(v.w + p.w);
  ((ushort4*)(X + (size_t)row * DIN_))[i] = o;
}

// ---------------- bf16 GEMM, C[m][n] = sum_k A[m][k]*B[n][k] + bias[n] ----------------
__global__ __launch_bounds__(256) void gemm_bt(const u16* __restrict__ A,
                                               const u16* __restrict__ Bm,
                                               const float* __restrict__ bias,
                                               u16* __restrict__ C,
                                               int M, int N, int K) {
  __shared__ __align__(16) u16 As[128 * 64];
  __shared__ __align__(16) u16 Bs[128 * 64];
  const int tid = threadIdx.x;
  const int lane = tid & 63;
  const int wave = tid >> 6;
  const int m0 = blockIdx.y * 128;
  const int n0 = blockIdx.x * 128;
  const int wm = (wave >> 1) * 64;
  const int wn = (wave & 1) * 64;
  const int lr = lane & 15;
  const int lg = lane >> 4;
  f32x4 acc[4][4] = {};

  for (int k0 = 0; k0 < K; k0 += 64) {
#pragma unroll
    for (int it = 0; it < 4; ++it) {
      int e = it * 256 + tid;
      int r = e >> 3, c8 = (e & 7) * 8;
      gload_lds16(A + (size_t)(m0 + r) * K + k0 + c8, &As[e * 8]);
      gload_lds16(Bm + (size_t)(n0 + r) * K + k0 + c8, &Bs[e * 8]);
    }
    __syncthreads();
#pragma unroll
    for (int kk = 0; kk < 64; kk += 32) {
      bf16x8 af[4], bfr[4];
#pragma unroll
      for (int i = 0; i < 4; ++i) {
        af[i]  = *(const bf16x8*)&As[(wm + i * 16 + lr) * 64 + kk + lg * 8];
        bfr[i] = *(const bf16x8*)&Bs[(wn + i * 16 + lr) * 64 + kk + lg * 8];
      }
#pragma unroll
      for (int i = 0; i < 4; ++i)
#pragma unroll
        for (int j = 0; j < 4; ++j)
          acc[i][j] = __builtin_amdgcn_mfma_f32_16x16x32_bf16(af[i], bfr[j], acc[i][j], 0, 0, 0);
    }
    __syncthreads();
  }
#pragma unroll
  for (int i = 0; i < 4; ++i) {
#pragma unroll
    for (int j = 0; j < 4; ++j) {
      int col = n0 + wn + j * 16 + lr;
      float bv = bias[col];
#pragma unroll
      for (int q = 0; q < 4; ++q) {
        int row = m0 + wm + i * 16 + lg * 4 + q;
        C[(size_t)row * N + col] = f2bf(acc[i][j][q] + bv);
      }
    }
  }
}

// stage 64 rows x 512 cols bf16 (row stride 512) into LDS, XOR-swizzled.
// PLAIN cached loads (R9 post-mortem): NT/atomic loads cap at ~1.7 TB/s chip-wide
// (R4/R6/R9 all measured it). Plain loads are safe here: every h address is
// written ONCE per call (NT store -> MALL) and read only after the flag; the
// dispatch-start acquire invalidated replay-stale lines, and NT stores don't
// populate consumer L2s -> first read per XCD misses to MALL (fresh), the
// duplicate reads hit the XCD-local L2 at full rate.
__device__ __forceinline__ void stage64(char* dst, const u16* src, int tid) {
  const u64* s64 = (const u64*)src;
#pragma unroll
  for (int i = 0; i < 16; ++i) {
    int e = i * 512 + tid, r = e >> 7, c8 = e & 127;
    u64 v = s64[(size_t)r * 128 + c8];
    *(u64*)(dst + r * 1024 + ((((c8 >> 1) ^ (r & 7)) << 4) | ((c8 & 1) << 3))) = v;
  }
}

// ---------------- fused dual-chain wavefront recurrence, v3 ----------------
// Identical structure to R9 (passed): 256 blocks cooperative, 1/CU.
//   bid [0,128):   L1 — h1(t) = act(Xpre(t) + R1 h1(t-1)),        K=512
//   bid [128,256): L2 — h2(t) = act(W2 h1(t) + R2 h2(t-1) + b2),  two phases
// ONLY change vs R9: stage64 uses plain cached loads (see above).
__global__ __launch_bounds__(512, 2) void lstm_duo2(
    const u16* __restrict__ Xpre,    // (S,256,2048) bf16, includes b1
    u16* __restrict__ H1,            // (S,256,512)
    u16* __restrict__ H2,            // (S,256,512)
    const u16* __restrict__ R1b,     // (2048,512)
    const u16* __restrict__ W2b,     // (2048,512)
    const u16* __restrict__ R2b,     // (2048,512)
    const float* __restrict__ b2,    // (2048,)
    u32* __restrict__ flag1, u32* __restrict__ flag2) {
  __shared__ __align__(16) char lds[131072];   // As1 [0,64K) | As2 [64K,128K)
  const int tid = threadIdx.x;
  const int lane = tid & 63;
  const int w = tid >> 6;
  const int lr = lane & 15, lg = lane >> 4;
  const int kind = blockIdx.x >> 7;            // 0=L1, 1=L2
  const int lb = blockIdx.x & 127;
  const int m4 = lb & 3, j32 = lb >> 2;
  const int m0 = m4 * 64, j0 = j32 * 16;
  const int g = w & 3, kh = w >> 2;            // wave = (gate, K-half)
  const int cr = tid >> 3, cc = (tid & 7) * 2; // epilogue cell ownership
  float* Gsf = (float*)lds;                    // [2][4][64][17] f32 overlay on As1
  char* As1 = lds;
  char* As2 = lds + 65536;

#define GS(KH, GG, RR, CC) Gsf[(((KH) * 4 + (GG)) * 64 + (RR)) * 17 + (CC)]

  if (kind == 0) {
    // =========================== L1 chain ===========================
    bf16x8 B1[8];
#pragma unroll
    for (int k = 0; k < 8; ++k)
      B1[k] = *(const bf16x8*)&R1b[(size_t)(g * 512 + j0 + lr) * 512 +
                                   kh * 256 + k * 32 + lg * 8];
    float cst0 = 0.f, cst1 = 0.f;

    for (int t = 0; t < SEQ_; ++t) {
      // prefetch Xpre(t) (read-only phase-A data, plain loads)
      u32 xp[4];
#pragma unroll
      for (int gg = 0; gg < 4; ++gg)
        xp[gg] = *(const u32*)(Xpre + (size_t)t * (BATCH_ * NG_) +
                               (size_t)(m0 + cr) * NG_ + gg * 512 + j0 + cc);
      if (t > 0) {
        if (w == 0) {   // poll own m-group's 32 sibling flags for h1(t-1)
          const u32* f = flag1 + (size_t)(t - 1) * 128 + m4 * 32 + (lane & 31);
          int spins = 0;
          while (!__all(aload32(f) != 0)) {
            __builtin_amdgcn_s_sleep(1);
            if (++spins > (1 << 20)) break;
          }
        }
        __syncthreads();
        stage64(As1, H1 + ((size_t)(t - 1) * BATCH_ + m0) * HID_, tid);
      }
      __syncthreads();
      f32x4 acc[4] = {};
      if (t > 0) {
#pragma unroll
        for (int rf = 0; rf < 4; ++rf) {
#pragma unroll
          for (int k = 0; k < 8; ++k) {
            int c = kh * 32 + k * 4 + lg;
            bf16x8 a = *(const bf16x8*)(As1 + (rf * 16 + lr) * 1024 +
                                        ((c ^ (lr & 7)) << 4));
            acc[rf] = __builtin_amdgcn_mfma_f32_16x16x32_bf16(a, B1[k], acc[rf], 0, 0, 0);
          }
        }
      }
      __syncthreads();   // As1 reads done -> Gs overlay safe
#pragma unroll
      for (int rf = 0; rf < 4; ++rf)
#pragma unroll
        for (int q = 0; q < 4; ++q)
          GS(kh, g, rf * 16 + lg * 4 + q, lr) = acc[rf][q];
      __syncthreads();
      {  // cell update: thread owns (cr, cc..cc+1)
        float G[4][2];
#pragma unroll
        for (int gg = 0; gg < 4; ++gg) {
          G[gg][0] = GS(0, gg, cr, cc) + GS(1, gg, cr, cc) + bf2f((u16)xp[gg]);
          G[gg][1] = GS(0, gg, cr, cc + 1) + GS(1, gg, cr, cc + 1) + bf2f((u16)(xp[gg] >> 16));
        }
        u32 pack = 0;
        {
          float iv = 1.f / (1.f + expf(-G[0][0]));
          float fv = 1.f / (1.f + expf(-G[1][0]));
          float mv = tanhf(G[2][0]);
          float ov = 1.f / (1.f + expf(-G[3][0]));
          float cn = mv * iv + fv * cst0; cst0 = cn;
          pack |= (u32)f2bf(ov * tanhf(cn));
        }
        {
          float iv = 1.f / (1.f + expf(-G[0][1]));
          float fv = 1.f / (1.f + expf(-G[1][1]));
          float mv = tanhf(G[2][1]);
          float ov = 1.f / (1.f + expf(-G[3][1]));
          float cn = mv * iv + fv * cst1; cst1 = cn;
          pack |= (u32)f2bf(ov * tanhf(cn)) << 16;
        }
        astore32((u32*)(H1 + (size_t)t * (BATCH_ * HID_) +
                        (size_t)(m0 + cr) * HID_ + j0 + cc), pack);  // NT -> MALL
      }
      __syncthreads();   // vmcnt(0) drain: h stores at MALL before flag
      if (tid == 0)
        astore32_rel(flag1 + (size_t)t * 128 + m4 * 32 + j32, 1u);
    }
  } else {
    // =========================== L2 chain ===========================
    bf16x8 W2f[8], R2f[8];
#pragma unroll
    for (int k = 0; k < 8; ++k) {
      size_t off = (size_t)(g * 512 + j0 + lr) * 512 + kh * 256 + k * 32 + lg * 8;
      W2f[k] = *(const bf16x8*)&W2b[off];
      R2f[k] = *(const bf16x8*)&R2b[off];
    }
    float bc[4][2];
#pragma unroll
    for (int gg = 0; gg < 4; ++gg) {
      bc[gg][0] = b2[gg * 512 + j0 + cc];
      bc[gg][1] = b2[gg * 512 + j0 + cc + 1];
    }
    float cst0 = 0.f, cst1 = 0.f;

    for (int t = 0; t < SEQ_; ++t) {
      f32x4 acc[4] = {};
      // ---- phase 1: R2 . h2(t-1) — own-chain flag is old, near-zero wait ----
      if (t > 0) {
        if (w == 0) {
          const u32* f = flag2 + (size_t)(t - 1) * 128 + m4 * 32 + (lane & 31);
          int spins = 0;
          while (!__all(aload32(f) != 0)) {
            __builtin_amdgcn_s_sleep(1);
            if (++spins > (1 << 20)) break;
          }
        }
        __syncthreads();
        stage64(As2, H2 + ((size_t)(t - 1) * BATCH_ + m0) * HID_, tid);
        __syncthreads();
#pragma unroll
        for (int rf = 0; rf < 4; ++rf) {
#pragma unroll
          for (int k = 0; k < 8; ++k) {
            int c = kh * 32 + k * 4 + lg;
            bf16x8 a = *(const bf16x8*)(As2 + (rf * 16 + lr) * 1024 +
                                        ((c ^ (lr & 7)) << 4));
            acc[rf] = __builtin_amdgcn_mfma_f32_16x16x32_bf16(a, R2f[k], acc[rf], 0, 0, 0);
          }
        }
      }
      // ---- phase 2: W2 . h1(t) — poll L1's flag only now ----
      if (w == 0) {
        const u32* f = flag1 + (size_t)t * 128 + m4 * 32 + (lane & 31);
        int spins = 0;
        while (!__all(aload32(f) != 0)) {
          __builtin_amdgcn_s_sleep(1);
          if (++spins > (1 << 20)) break;
        }
      }
      __syncthreads();
      stage64(As1, H1 + ((size_t)t * BATCH_ + m0) * HID_, tid);  // overwrites old Gs (dead)
      __syncthreads();
#pragma unroll
      for (int rf = 0; rf < 4; ++rf) {
#pragma unroll
        for (int k = 0; k < 8; ++k) {
          int c = kh * 32 + k * 4 + lg;
          bf16x8 a = *(const bf16x8*)(As1 + (rf * 16 + lr) * 1024 +
                                      ((c ^ (lr & 7)) << 4));
          acc[rf] = __builtin_amdgcn_mfma_f32_16x16x32_bf16(a, W2f[k], acc[rf], 0, 0, 0);
        }
      }
      __syncthreads();   // As1 reads done -> Gs overlay safe
#pragma unroll
      for (int rf = 0; rf < 4; ++rf)
#pragma unroll
        for (int q = 0; q < 4; ++q)
          GS(kh, g, rf * 16 + lg * 4 + q, lr) = acc[rf][q];
      __syncthreads();
      {
        float G[4][2];
#pragma unroll
        for (int gg = 0; gg < 4; ++gg) {
          G[gg][0] = GS(0, gg, cr, cc) + GS(1, gg, cr, cc) + bc[gg][0];
          G[gg][1] = GS(0, gg, cr, cc + 1) + GS(1, gg, cr, cc + 1) + bc[gg][1];
        }
        u32 pack = 0;
        {
          float iv = 1.f / (1.f + expf(-G[0][0]));
          float fv = 1.f / (1.f + expf(-G[1][0]));
          float mv = tanhf(G[2][0]);
          float ov = 1.f / (1.f + expf(-G[3][0]));
          float cn = mv * iv + fv * cst0; cst0 = cn;
          pack |= (u32)f2bf(ov * tanhf(cn));
        }
        {
          float iv = 1.f / (1.f + expf(-G[0][1]));
          float fv = 1.f / (1.f + expf(-G[1][1]));
          float mv = tanhf(G[2][1]);
          float ov = 1.f / (1.f + expf(-G[3][1]));
          float cn = mv * iv + fv * cst1; cst1 = cn;
          pack |= (u32)f2bf(ov * tanhf(cn)) << 16;
        }
        astore32((u32*)(H2 + (size_t)t * (BATCH_ * HID_) +
                        (size_t)(m0 + cr) * HID_ + j0 + cc), pack);
      }
      __syncthreads();
      if (tid == 0)
        astore32_rel(flag2 + (size_t)t * 128 + m4 * 32 + j32, 1u);
    }
  }
#undef GS
}

// ---------------- output projection: out[b][t][cls] = h2 . Wo[cls] + bo ----------------
__global__ __launch_bounds__(320) void out_proj(const u16* __restrict__ H2,
                                                const float* __restrict__ Wo,
                                                const float* __restrict__ bo,
                                                float* __restrict__ out) {
  __shared__ __align__(16) u16 Hs[32 * 520];
  const int r0 = blockIdx.x * 32;     // flat row = t*256 + b
  const int tid = threadIdx.x;
  for (int e = tid; e < 2048; e += 320) {
    int rl = e >> 6, k8 = (e & 63) * 8;
    *(uint4*)&Hs[rl * 520 + k8] = *(const uint4*)(H2 + (size_t)(r0 + rl) * HID_ + k8);
  }
  __syncthreads();
  if (tid < 288) {
    int rl = tid / 9, cls = tid - rl * 9;
    const u16* h = &Hs[rl * 520];
    const float* wv = Wo + cls * HID_;
    float s = bo[cls];
#pragma unroll 8
    for (int k = 0; k < HID_; ++k) s += bf2f(h[k]) * wv[k];
    int r = r0 + rl, t = r >> 8, b = r & 255;
    out[((size_t)b * SEQ_ + t) * NCLS_ + cls] = s;
  }
}

extern "C" void kernel_launch(void* const* d_in, const int* in_sizes, int n_in,
                              void* d_out, int out_size, void* d_ws, size_t ws_size,
                              hipStream_t stream) {
  (void)in_sizes; (void)n_in; (void)out_size; (void)ws_size;
  const int*   ids = (const int*)d_in[0];
  const float* tok = (const float*)d_in[1];
  const float* pos = (const float*)d_in[2];
  const float* W1  = (const float*)d_in[3];
  const float* R1  = (const float*)d_in[4];
  const float* b1  = (const float*)d_in[5];
  const float* W2  = (const float*)d_in[6];
  const float* R2  = (const float*)d_in[7];
  const float* b2  = (const float*)d_in[8];
  const float* Wo  = (const float*)d_in[9];
  const float* bo  = (const float*)d_in[10];
  float* out = (float*)d_out;

  // workspace (~226 MB); H1all overlays Xbf (dead after phase A)
  char* p = (char*)d_ws;
  auto alloc = [&](size_t bytes) { char* q = p; p += (bytes + 255) & ~(size_t)255; return q; };
  u16*  W1b  = (u16*)alloc((size_t)NG_ * DIN_ * 2);                 // 3MB
  u16*  R1b  = (u16*)alloc((size_t)NG_ * HID_ * 2);                 // 2MB
  u16*  W2b  = (u16*)alloc((size_t)NG_ * HID_ * 2);                 // 2MB
  u16*  R2b  = (u16*)alloc((size_t)NG_ * HID_ * 2);                 // 2MB
  u32*  flag1 = (u32*)alloc((size_t)SEQ_ * 128 * 4);                // 64KB
  u32*  flag2 = (u32*)alloc((size_t)SEQ_ * 128 * 4);                // 64KB
  size_t xbf_bytes = (size_t)SEQ_ * BATCH_ * DIN_ * 2;              // 50.3MB
  u16*  Xbf  = (u16*)alloc(xbf_bytes);
  u16*  H1all = Xbf;                                                // overlay (32MB < 50.3MB)
  u16*  H2all = (u16*)alloc((size_t)SEQ_ * BATCH_ * HID_ * 2);      // 32MB
  u16*  Xpre = (u16*)alloc((size_t)SEQ_ * BATCH_ * NG_ * 2);        // 134MB

  // weight casts
  castk<<<dim3((NG_ * DIN_ / 4 + 255) / 256), 256, 0, stream>>>(W1, W1b, NG_ * DIN_ / 4);
  castk<<<dim3((NG_ * HID_ / 4 + 255) / 256), 256, 0, stream>>>(R1, R1b, NG_ * HID_ / 4);
  castk<<<dim3((NG_ * HID_ / 4 + 255) / 256), 256, 0, stream>>>(W2, W2b, NG_ * HID_ / 4);
  castk<<<dim3((NG_ * HID_ / 4 + 255) / 256), 256, 0, stream>>>(R2, R2b, NG_ * HID_ / 4);
  // flags must be zero each call (graph replays re-run this memset)
  hipMemsetAsync(flag1, 0, (size_t)SEQ_ * 256 * 4, stream);  // flag1+flag2 contiguous

  // embeds -> (S,B,768) bf16
  embed_k<<<dim3(SEQ_ * BATCH_), 192, 0, stream>>>(ids, tok, pos, Xbf);

  // phase A: Xpre = X @ W1^T + b1   (32768 x 2048, K=768)
  gemm_bt<<<dim3(NG_ / 128, SEQ_ * BATCH_ / 128), 256, 0, stream>>>(
      Xbf, W1b, b1, Xpre, SEQ_ * BATCH_, NG_, DIN_);

  // fused dual-chain recurrence (cooperative: co-residency for spin-wait)
  {
    const u16* Xp = Xpre; u16* H1a = H1all; u16* H2a = H2all;
    const u16* R1a = R1b; const u16* W2a = W2b; const u16* R2a = R2b;
    const float* b2a = b2;
    u32* f1 = flag1; u32* f2 = flag2;
    void* args[] = {(void*)&Xp, (void*)&H1a, (void*)&H2a, (void*)&R1a,
                    (void*)&W2a, (void*)&R2a, (void*)&b2a, (void*)&f1, (void*)&f2};
    hipLaunchCooperativeKernel(reinterpret_cast<void*>(&lstm_duo2),
                               dim3(256), dim3(512), args, 0, stream);
  }

  // logits
  out_proj<<<dim3(SEQ_ * BATCH_ / 32), 320, 0, stream>>>(H2all, Wo, bo, out);
}

// Round 11
// 1109.501 us; speedup vs baseline: 2.3328x; 1.3834x over previous
//
#include <hip/hip_runtime.h>
#include <hip/hip_bf16.h>
#include <stdint.h>

// Problem constants
#define BATCH_ 256
#define SEQ_   128
#define DIN_   768
#define HID_   512
#define NG_    2048   // 4*HID
#define NCLS_  9

typedef unsigned short u16;
typedef unsigned int u32;
typedef unsigned long long u64;
typedef __attribute__((ext_vector_type(8))) short bf16x8;
typedef __attribute__((ext_vector_type(4))) float f32x4;

__device__ __forceinline__ float bf2f(u16 u) {
  return __builtin_bit_cast(float, (uint32_t)u << 16);
}
__device__ __forceinline__ u16 f2bf(float f) {
  uint32_t x = __builtin_bit_cast(uint32_t, f);
  uint32_t r = (x + 0x7fffu + ((x >> 16) & 1u)) >> 16;  // RNE
  return (u16)r;
}

// async global->LDS, 16B per lane (gemm_bt staging only)
__device__ __forceinline__ void gload_lds16(const void* g, void* l) {
#if defined(__has_builtin)
#if __has_builtin(__builtin_amdgcn_global_load_lds)
  __builtin_amdgcn_global_load_lds((const __attribute__((address_space(1))) void*)g,
                                   (__attribute__((address_space(3))) void*)l, 16, 0, 0);
  return;
#endif
#endif
  *(uint4*)l = *(const uint4*)g;  // fallback
}

__device__ __forceinline__ u32 aload32(const u32* p) {
  return __hip_atomic_load(p, __ATOMIC_RELAXED, __HIP_MEMORY_SCOPE_AGENT);
}
__device__ __forceinline__ void astore32(u32* p, u32 v) {
  __hip_atomic_store(p, v, __ATOMIC_RELAXED, __HIP_MEMORY_SCOPE_AGENT);
}

// ---------------- f32 -> bf16 cast (weights) ----------------
__global__ void castk(const float* __restrict__ s, u16* __restrict__ d, int n4) {
  int i = blockIdx.x * blockDim.x + threadIdx.x;
  if (i < n4) {
    float4 v = ((const float4*)s)[i];
    ushort4 o;
    o.x = f2bf(v.x); o.y = f2bf(v.y); o.z = f2bf(v.z); o.w = f2bf(v.w);
    ((ushort4*)d)[i] = o;
  }
}

// ---------------- embed gather + add pos + cast, (S,B,768) bf16 ----------------
__global__ __launch_bounds__(192) void embed_k(const int* __restrict__ ids,
                                               const float* __restrict__ tok,
                                               const float* __restrict__ pos,
                                               u16* __restrict__ X) {
  const int row = blockIdx.x;          // row = t*256 + b
  const int t = row >> 8, b = row & 255;
  const int id = ids[b * SEQ_ + t];    // input_ids is (B,S)
  const float4* tr = (const float4*)(tok + (size_t)id * DIN_);
  const float4* pr = (const float4*)(pos + (size_t)t * DIN_);
  const int i = threadIdx.x;
  float4 v = tr[i], p = pr[i];
  ushort4 o;
  o.x = f2bf(v.x + p.x); o.y = f2bf(v.y + p.y);
  o.z = f2bf(v.z + p.z); o.w = f2bf(v.w + p.w);
  ((ushort4*)(X + (size_t)row * DIN_))[i] = o;
}

// ---------------- bf16 GEMM, C[m][n] = sum_k A[m][k]*B[n][k] + bias[n] ----------------
__global__ __launch_bounds__(256) void gemm_bt(const u16* __restrict__ A,
                                               const u16* __restrict__ Bm,
                                               const float* __restrict__ bias,
                                               u16* __restrict__ C,
                                               int M, int N, int K) {
  __shared__ __align__(16) u16 As[128 * 64];
  __shared__ __align__(16) u16 Bs[128 * 64];
  const int tid = threadIdx.x;
  const int lane = tid & 63;
  const int wave = tid >> 6;
  const int m0 = blockIdx.y * 128;
  const int n0 = blockIdx.x * 128;
  const int wm = (wave >> 1) * 64;
  const int wn = (wave & 1) * 64;
  const int lr = lane & 15;
  const int lg = lane >> 4;
  f32x4 acc[4][4] = {};

  for (int k0 = 0; k0 < K; k0 += 64) {
#pragma unroll
    for (int it = 0; it < 4; ++it) {
      int e = it * 256 + tid;
      int r = e >> 3, c8 = (e & 7) * 8;
      gload_lds16(A + (size_t)(m0 + r) * K + k0 + c8, &As[e * 8]);
      gload_lds16(Bm + (size_t)(n0 + r) * K + k0 + c8, &Bs[e * 8]);
    }
    __syncthreads();
#pragma unroll
    for (int kk = 0; kk < 64; kk += 32) {
      bf16x8 af[4], bfr[4];
#pragma unroll
      for (int i = 0; i < 4; ++i) {
        af[i]  = *(const bf16x8*)&As[(wm + i * 16 + lr) * 64 + kk + lg * 8];
        bfr[i] = *(const bf16x8*)&Bs[(wn + i * 16 + lr) * 64 + kk + lg * 8];
      }
#pragma unroll
      for (int i = 0; i < 4; ++i)
#pragma unroll
        for (int j = 0; j < 4; ++j)
          acc[i][j] = __builtin_amdgcn_mfma_f32_16x16x32_bf16(af[i], bfr[j], acc[i][j], 0, 0, 0);
    }
    __syncthreads();
  }
#pragma unroll
  for (int i = 0; i < 4; ++i) {
#pragma unroll
    for (int j = 0; j < 4; ++j) {
      int col = n0 + wn + j * 16 + lr;
      float bv = bias[col];
#pragma unroll
      for (int q = 0; q < 4; ++q) {
        int row = m0 + wm + i * 16 + lg * 4 + q;
        C[(size_t)row * N + col] = f2bf(acc[i][j][q] + bv);
      }
    }
  }
}

// stage 64 rows x 512 cols bf16 (row stride 512) into LDS, XOR-swizzled.
// PLAIN cached loads (R9/R10-proven): NT stores bypass producer L2 and the
// consumer never cached these (write-once) addresses -> first read per XCD
// misses to MALL (fresh), duplicate reads hit the XCD-local L2 at full rate.
__device__ __forceinline__ void stage64(char* dst, const u16* src, int tid) {
  const u64* s64 = (const u64*)src;
#pragma unroll
  for (int i = 0; i < 16; ++i) {
    int e = i * 512 + tid, r = e >> 7, c8 = e & 127;
    u64 v = s64[(size_t)r * 128 + c8];
    *(u64*)(dst + r * 1024 + ((((c8 >> 1) ^ (r & 7)) << 4) | ((c8 & 1) << 3))) = v;
  }
}

// ---------------- fused dual-chain wavefront recurrence, v4 ----------------
// 256 blocks (cooperative, 1/CU via 128KB LDS), 512 threads.
//   bid [0,128):   L1 — h1(t) = act(Xpre(t) + R1 h1(t-1)),        K=512
//   bid [128,256): L2 — h2(t) = act(W2 h1(t) + R2 h2(t-1) + b2),  K=512+512
// Changes vs R10 (passed, 1250us):
//  (1) L2 phases FUSED: one combined poll (flag1(t) + flag2(t-1)), one stage of
//      both h slabs, one MFMA block — drops 2 barrier-drain round trips + 1 poll
//      per step. R6 proved the fused structure; it only lost on NT-load BW,
//      which R10 removed.
//  (2) flags stored RELAXED (R4-proven): the __syncthreads vmcnt(0) drain already
//      guarantees all NT h-stores completed at MALL before tid0's flag store;
//      release's buffer_wbl2 is pure overhead for NT data.
__global__ __launch_bounds__(512, 2) void lstm_duo2(
    const u16* __restrict__ Xpre,    // (S,256,2048) bf16, includes b1
    u16* __restrict__ H1,            // (S,256,512)
    u16* __restrict__ H2,            // (S,256,512)
    const u16* __restrict__ R1b,     // (2048,512)
    const u16* __restrict__ W2b,     // (2048,512)
    const u16* __restrict__ R2b,     // (2048,512)
    const float* __restrict__ b2,    // (2048,)
    u32* __restrict__ flag1, u32* __restrict__ flag2) {
  __shared__ __align__(16) char lds[131072];   // As1 [0,64K) | As2 [64K,128K)
  const int tid = threadIdx.x;
  const int lane = tid & 63;
  const int w = tid >> 6;
  const int lr = lane & 15, lg = lane >> 4;
  const int kind = blockIdx.x >> 7;            // 0=L1, 1=L2
  const int lb = blockIdx.x & 127;
  const int m4 = lb & 3, j32 = lb >> 2;
  const int m0 = m4 * 64, j0 = j32 * 16;
  const int g = w & 3, kh = w >> 2;            // wave = (gate, K-half)
  const int cr = tid >> 3, cc = (tid & 7) * 2; // epilogue cell ownership
  float* Gsf = (float*)lds;                    // [2][4][64][17] f32 overlay on As1
  char* As1 = lds;
  char* As2 = lds + 65536;

#define GS(KH, GG, RR, CC) Gsf[(((KH) * 4 + (GG)) * 64 + (RR)) * 17 + (CC)]

  if (kind == 0) {
    // =========================== L1 chain ===========================
    bf16x8 B1[8];
#pragma unroll
    for (int k = 0; k < 8; ++k)
      B1[k] = *(const bf16x8*)&R1b[(size_t)(g * 512 + j0 + lr) * 512 +
                                   kh * 256 + k * 32 + lg * 8];
    float cst0 = 0.f, cst1 = 0.f;

    for (int t = 0; t < SEQ_; ++t) {
      // prefetch Xpre(t) (read-only phase-A data, plain loads; hides under poll)
      u32 xp[4];
#pragma unroll
      for (int gg = 0; gg < 4; ++gg)
        xp[gg] = *(const u32*)(Xpre + (size_t)t * (BATCH_ * NG_) +
                               (size_t)(m0 + cr) * NG_ + gg * 512 + j0 + cc);
      if (t > 0) {
        if (w == 0) {   // poll own m-group's 32 sibling flags for h1(t-1)
          const u32* f = flag1 + (size_t)(t - 1) * 128 + m4 * 32 + (lane & 31);
          int spins = 0;
          while (!__all(aload32(f) != 0)) {
            __builtin_amdgcn_s_sleep(1);
            if (++spins > (1 << 20)) break;
          }
        }
        __syncthreads();
        stage64(As1, H1 + ((size_t)(t - 1) * BATCH_ + m0) * HID_, tid);
      }
      __syncthreads();
      f32x4 acc[4] = {};
      if (t > 0) {
#pragma unroll
        for (int rf = 0; rf < 4; ++rf) {
#pragma unroll
          for (int k = 0; k < 8; ++k) {
            int c = kh * 32 + k * 4 + lg;
            bf16x8 a = *(const bf16x8*)(As1 + (rf * 16 + lr) * 1024 +
                                        ((c ^ (lr & 7)) << 4));
            acc[rf] = __builtin_amdgcn_mfma_f32_16x16x32_bf16(a, B1[k], acc[rf], 0, 0, 0);
          }
        }
      }
      __syncthreads();   // As1 reads done -> Gs overlay safe
#pragma unroll
      for (int rf = 0; rf < 4; ++rf)
#pragma unroll
        for (int q = 0; q < 4; ++q)
          GS(kh, g, rf * 16 + lg * 4 + q, lr) = acc[rf][q];
      __syncthreads();
      {  // cell update: thread owns (cr, cc..cc+1)
        float G[4][2];
#pragma unroll
        for (int gg = 0; gg < 4; ++gg) {
          G[gg][0] = GS(0, gg, cr, cc) + GS(1, gg, cr, cc) + bf2f((u16)xp[gg]);
          G[gg][1] = GS(0, gg, cr, cc + 1) + GS(1, gg, cr, cc + 1) + bf2f((u16)(xp[gg] >> 16));
        }
        u32 pack = 0;
        {
          float iv = 1.f / (1.f + expf(-G[0][0]));
          float fv = 1.f / (1.f + expf(-G[1][0]));
          float mv = tanhf(G[2][0]);
          float ov = 1.f / (1.f + expf(-G[3][0]));
          float cn = mv * iv + fv * cst0; cst0 = cn;
          pack |= (u32)f2bf(ov * tanhf(cn));
        }
        {
          float iv = 1.f / (1.f + expf(-G[0][1]));
          float fv = 1.f / (1.f + expf(-G[1][1]));
          float mv = tanhf(G[2][1]);
          float ov = 1.f / (1.f + expf(-G[3][1]));
          float cn = mv * iv + fv * cst1; cst1 = cn;
          pack |= (u32)f2bf(ov * tanhf(cn)) << 16;
        }
        astore32((u32*)(H1 + (size_t)t * (BATCH_ * HID_) +
                        (size_t)(m0 + cr) * HID_ + j0 + cc), pack);  // NT -> MALL
      }
      __syncthreads();   // vmcnt(0) drain: all h stores at MALL before flag
      if (tid == 0)
        astore32(flag1 + (size_t)t * 128 + m4 * 32 + j32, 1u);
    }
  } else {
    // =========================== L2 chain (fused phases) ===========================
    bf16x8 W2f[8], R2f[8];
#pragma unroll
    for (int k = 0; k < 8; ++k) {
      size_t off = (size_t)(g * 512 + j0 + lr) * 512 + kh * 256 + k * 32 + lg * 8;
      W2f[k] = *(const bf16x8*)&W2b[off];
      R2f[k] = *(const bf16x8*)&R2b[off];
    }
    float bc[4][2];
#pragma unroll
    for (int gg = 0; gg < 4; ++gg) {
      bc[gg][0] = b2[gg * 512 + j0 + cc];
      bc[gg][1] = b2[gg * 512 + j0 + cc + 1];
    }
    float cst0 = 0.f, cst1 = 0.f;

    for (int t = 0; t < SEQ_; ++t) {
      // combined poll: lanes 0-31 flag1(t) (ready ahead at steady state),
      //                lanes 32-63 flag2(t-1) (own chain)
      if (w == 0) {
        const u32* fa = flag1 + (size_t)t * 128 + m4 * 32 + (lane & 31);
        const u32* fb = flag2 + (size_t)(t > 0 ? t - 1 : 0) * 128 + m4 * 32 + (lane & 31);
        int spins = 0;
        while (true) {
          u32 v = (lane < 32) ? aload32(fa) : ((t > 0) ? aload32(fb) : 1u);
          if (__all(v != 0)) break;
          __builtin_amdgcn_s_sleep(1);
          if (++spins > (1 << 20)) break;
        }
      }
      __syncthreads();
      // stage both h slabs back-to-back (loads pipeline together)
      stage64(As1, H1 + ((size_t)t * BATCH_ + m0) * HID_, tid);
      if (t > 0)
        stage64(As2, H2 + ((size_t)(t - 1) * BATCH_ + m0) * HID_, tid);
      __syncthreads();
      f32x4 acc[4] = {};
#pragma unroll
      for (int rf = 0; rf < 4; ++rf) {   // W2 . h1(t)
#pragma unroll
        for (int k = 0; k < 8; ++k) {
          int c = kh * 32 + k * 4 + lg;
          bf16x8 a = *(const bf16x8*)(As1 + (rf * 16 + lr) * 1024 +
                                      ((c ^ (lr & 7)) << 4));
          acc[rf] = __builtin_amdgcn_mfma_f32_16x16x32_bf16(a, W2f[k], acc[rf], 0, 0, 0);
        }
      }
      if (t > 0) {
#pragma unroll
        for (int rf = 0; rf < 4; ++rf) {  // R2 . h2(t-1)
#pragma unroll
          for (int k = 0; k < 8; ++k) {
            int c = kh * 32 + k * 4 + lg;
            bf16x8 a = *(const bf16x8*)(As2 + (rf * 16 + lr) * 1024 +
                                        ((c ^ (lr & 7)) << 4));
            acc[rf] = __builtin_amdgcn_mfma_f32_16x16x32_bf16(a, R2f[k], acc[rf], 0, 0, 0);
          }
        }
      }
      __syncthreads();   // As reads done -> Gs overlay safe
#pragma unroll
      for (int rf = 0; rf < 4; ++rf)
#pragma unroll
        for (int q = 0; q < 4; ++q)
          GS(kh, g, rf * 16 + lg * 4 + q, lr) = acc[rf][q];
      __syncthreads();
      {
        float G[4][2];
#pragma unroll
        for (int gg = 0; gg < 4; ++gg) {
          G[gg][0] = GS(0, gg, cr, cc) + GS(1, gg, cr, cc) + bc[gg][0];
          G[gg][1] = GS(0, gg, cr, cc + 1) + GS(1, gg, cr, cc + 1) + bc[gg][1];
        }
        u32 pack = 0;
        {
          float iv = 1.f / (1.f + expf(-G[0][0]));
          float fv = 1.f / (1.f + expf(-G[1][0]));
          float mv = tanhf(G[2][0]);
          float ov = 1.f / (1.f + expf(-G[3][0]));
          float cn = mv * iv + fv * cst0; cst0 = cn;
          pack |= (u32)f2bf(ov * tanhf(cn));
        }
        {
          float iv = 1.f / (1.f + expf(-G[0][1]));
          float fv = 1.f / (1.f + expf(-G[1][1]));
          float mv = tanhf(G[2][1]);
          float ov = 1.f / (1.f + expf(-G[3][1]));
          float cn = mv * iv + fv * cst1; cst1 = cn;
          pack |= (u32)f2bf(ov * tanhf(cn)) << 16;
        }
        astore32((u32*)(H2 + (size_t)t * (BATCH_ * HID_) +
                        (size_t)(m0 + cr) * HID_ + j0 + cc), pack);
      }
      __syncthreads();
      if (tid == 0)
        astore32(flag2 + (size_t)t * 128 + m4 * 32 + j32, 1u);
    }
  }
#undef GS
}

// ---------------- output projection: out[b][t][cls] = h2 . Wo[cls] + bo ----------------
__global__ __launch_bounds__(320) void out_proj(const u16* __restrict__ H2,
                                                const float* __restrict__ Wo,
                                                const float* __restrict__ bo,
                                                float* __restrict__ out) {
  __shared__ __align__(16) u16 Hs[32 * 520];
  const int r0 = blockIdx.x * 32;     // flat row = t*256 + b
  const int tid = threadIdx.x;
  for (int e = tid; e < 2048; e += 320) {
    int rl = e >> 6, k8 = (e & 63) * 8;
    *(uint4*)&Hs[rl * 520 + k8] = *(const uint4*)(H2 + (size_t)(r0 + rl) * HID_ + k8);
  }
  __syncthreads();
  if (tid < 288) {
    int rl = tid / 9, cls = tid - rl * 9;
    const u16* h = &Hs[rl * 520];
    const float* wv = Wo + cls * HID_;
    float s = bo[cls];
#pragma unroll 8
    for (int k = 0; k < HID_; ++k) s += bf2f(h[k]) * wv[k];
    int r = r0 + rl, t = r >> 8, b = r & 255;
    out[((size_t)b * SEQ_ + t) * NCLS_ + cls] = s;
  }
}

extern "C" void kernel_launch(void* const* d_in, const int* in_sizes, int n_in,
                              void* d_out, int out_size, void* d_ws, size_t ws_size,
                              hipStream_t stream) {
  (void)in_sizes; (void)n_in; (void)out_size; (void)ws_size;
  const int*   ids = (const int*)d_in[0];
  const float* tok = (const float*)d_in[1];
  const float* pos = (const float*)d_in[2];
  const float* W1  = (const float*)d_in[3];
  const float* R1  = (const float*)d_in[4];
  const float* b1  = (const float*)d_in[5];
  const float* W2  = (const float*)d_in[6];
  const float* R2  = (const float*)d_in[7];
  const float* b2  = (const float*)d_in[8];
  const float* Wo  = (const float*)d_in[9];
  const float* bo  = (const float*)d_in[10];
  float* out = (float*)d_out;

  // workspace (~226 MB); H1all overlays Xbf (dead after phase A)
  char* p = (char*)d_ws;
  auto alloc = [&](size_t bytes) { char* q = p; p += (bytes + 255) & ~(size_t)255; return q; };
  u16*  W1b  = (u16*)alloc((size_t)NG_ * DIN_ * 2);                 // 3MB
  u16*  R1b  = (u16*)alloc((size_t)NG_ * HID_ * 2);                 // 2MB
  u16*  W2b  = (u16*)alloc((size_t)NG_ * HID_ * 2);                 // 2MB
  u16*  R2b  = (u16*)alloc((size_t)NG_ * HID_ * 2);                 // 2MB
  u32*  flag1 = (u32*)alloc((size_t)SEQ_ * 128 * 4);                // 64KB
  u32*  flag2 = (u32*)alloc((size_t)SEQ_ * 128 * 4);                // 64KB
  size_t xbf_bytes = (size_t)SEQ_ * BATCH_ * DIN_ * 2;              // 50.3MB
  u16*  Xbf  = (u16*)alloc(xbf_bytes);
  u16*  H1all = Xbf;                                                // overlay (32MB < 50.3MB)
  u16*  H2all = (u16*)alloc((size_t)SEQ_ * BATCH_ * HID_ * 2);      // 32MB
  u16*  Xpre = (u16*)alloc((size_t)SEQ_ * BATCH_ * NG_ * 2);        // 134MB

  // weight casts
  castk<<<dim3((NG_ * DIN_ / 4 + 255) / 256), 256, 0, stream>>>(W1, W1b, NG_ * DIN_ / 4);
  castk<<<dim3((NG_ * HID_ / 4 + 255) / 256), 256, 0, stream>>>(R1, R1b, NG_ * HID_ / 4);
  castk<<<dim3((NG_ * HID_ / 4 + 255) / 256), 256, 0, stream>>>(W2, W2b, NG_ * HID_ / 4);
  castk<<<dim3((NG_ * HID_ / 4 + 255) / 256), 256, 0, stream>>>(R2, R2b, NG_ * HID_ / 4);
  // flags must be zero each call (graph replays re-run this memset)
  hipMemsetAsync(flag1, 0, (size_t)SEQ_ * 256 * 4, stream);  // flag1+flag2 contiguous

  // embeds -> (S,B,768) bf16
  embed_k<<<dim3(SEQ_ * BATCH_), 192, 0, stream>>>(ids, tok, pos, Xbf);

  // phase A: Xpre = X @ W1^T + b1   (32768 x 2048, K=768)
  gemm_bt<<<dim3(NG_ / 128, SEQ_ * BATCH_ / 128), 256, 0, stream>>>(
      Xbf, W1b, b1, Xpre, SEQ_ * BATCH_, NG_, DIN_);

  // fused dual-chain recurrence (cooperative: co-residency for spin-wait)
  {
    const u16* Xp = Xpre; u16* H1a = H1all; u16* H2a = H2all;
    const u16* R1a = R1b; const u16* W2a = W2b; const u16* R2a = R2b;
    const float* b2a = b2;
    u32* f1 = flag1; u32* f2 = flag2;
    void* args[] = {(void*)&Xp, (void*)&H1a, (void*)&H2a, (void*)&R1a,
                    (void*)&W2a, (void*)&R2a, (void*)&b2a, (void*)&f1, (void*)&f2};
    hipLaunchCooperativeKernel(reinterpret_cast<void*>(&lstm_duo2),
                               dim3(256), dim3(512), args, 0, stream);
  }

  // logits
  out_proj<<<dim3(SEQ_ * BATCH_ / 32), 320, 0, stream>>>(H2all, Wo, bo, out);
}

// Round 12
// 913.106 us; speedup vs baseline: 2.8345x; 1.2151x over previous
//
#include <hip/hip_runtime.h>
#include <hip/hip_bf16.h>
#include <stdint.h>

// Problem constants
#define BATCH_ 256
#define SEQ_   128
#define DIN_   768
#define HID_   512
#define NG_    2048   // 4*HID
#define NCLS_  9

typedef unsigned short u16;
typedef unsigned int u32;
typedef unsigned long long u64;
typedef __attribute__((ext_vector_type(8))) short bf16x8;
typedef __attribute__((ext_vector_type(4))) float f32x4;

__device__ __forceinline__ float bf2f(u16 u) {
  return __builtin_bit_cast(float, (uint32_t)u << 16);
}
__device__ __forceinline__ u16 f2bf(float f) {
  uint32_t x = __builtin_bit_cast(uint32_t, f);
  uint32_t r = (x + 0x7fffu + ((x >> 16) & 1u)) >> 16;  // RNE
  return (u16)r;
}

// async global->LDS, 16B per lane (gemm_bt staging only)
__device__ __forceinline__ void gload_lds16(const void* g, void* l) {
#if defined(__has_builtin)
#if __has_builtin(__builtin_amdgcn_global_load_lds)
  __builtin_amdgcn_global_load_lds((const __attribute__((address_space(1))) void*)g,
                                   (__attribute__((address_space(3))) void*)l, 16, 0, 0);
  return;
#endif
#endif
  *(uint4*)l = *(const uint4*)g;  // fallback
}

__device__ __forceinline__ u32 aload32(const u32* p) {
  return __hip_atomic_load(p, __ATOMIC_RELAXED, __HIP_MEMORY_SCOPE_AGENT);
}
__device__ __forceinline__ void astore32(u32* p, u32 v) {
  __hip_atomic_store(p, v, __ATOMIC_RELAXED, __HIP_MEMORY_SCOPE_AGENT);
}

// ---------------- f32 -> bf16 cast (weights) ----------------
__global__ void castk(const float* __restrict__ s, u16* __restrict__ d, int n4) {
  int i = blockIdx.x * blockDim.x + threadIdx.x;
  if (i < n4) {
    float4 v = ((const float4*)s)[i];
    ushort4 o;
    o.x = f2bf(v.x); o.y = f2bf(v.y); o.z = f2bf(v.z); o.w = f2bf(v.w);
    ((ushort4*)d)[i] = o;
  }
}

// ---------------- embed gather + add pos + cast, (S,B,768) bf16 ----------------
__global__ __launch_bounds__(192) void embed_k(const int* __restrict__ ids,
                                               const float* __restrict__ tok,
                                               const float* __restrict__ pos,
                                               u16* __restrict__ X) {
  const int row = blockIdx.x;          // row = t*256 + b
  const int t = row >> 8, b = row & 255;
  const int id = ids[b * SEQ_ + t];    // input_ids is (B,S)
  const float4* tr = (const float4*)(tok + (size_t)id * DIN_);
  const float4* pr = (const float4*)(pos + (size_t)t * DIN_);
  const int i = threadIdx.x;
  float4 v = tr[i], p = pr[i];
  ushort4 o;
  o.x = f2bf(v.x + p.x); o.y = f2bf(v.y + p.y);
  o.z = f2bf(v.z + p.z); o.w = f2bf(v.w + p.w);
  ((ushort4*)(X + (size_t)row * DIN_))[i] = o;
}

// ---------------- bf16 GEMM, C[m][n] = sum_k A[m][k]*B[n][k] + bias[n] ----------------
__global__ __launch_bounds__(256) void gemm_bt(const u16* __restrict__ A,
                                               const u16* __restrict__ Bm,
                                               const float* __restrict__ bias,
                                               u16* __restrict__ C,
                                               int M, int N, int K) {
  __shared__ __align__(16) u16 As[128 * 64];
  __shared__ __align__(16) u16 Bs[128 * 64];
  const int tid = threadIdx.x;
  const int lane = tid & 63;
  const int wave = tid >> 6;
  const int m0 = blockIdx.y * 128;
  const int n0 = blockIdx.x * 128;
  const int wm = (wave >> 1) * 64;
  const int wn = (wave & 1) * 64;
  const int lr = lane & 15;
  const int lg = lane >> 4;
  f32x4 acc[4][4] = {};

  for (int k0 = 0; k0 < K; k0 += 64) {
#pragma unroll
    for (int it = 0; it < 4; ++it) {
      int e = it * 256 + tid;
      int r = e >> 3, c8 = (e & 7) * 8;
      gload_lds16(A + (size_t)(m0 + r) * K + k0 + c8, &As[e * 8]);
      gload_lds16(Bm + (size_t)(n0 + r) * K + k0 + c8, &Bs[e * 8]);
    }
    __syncthreads();
#pragma unroll
    for (int kk = 0; kk < 64; kk += 32) {
      bf16x8 af[4], bfr[4];
#pragma unroll
      for (int i = 0; i < 4; ++i) {
        af[i]  = *(const bf16x8*)&As[(wm + i * 16 + lr) * 64 + kk + lg * 8];
        bfr[i] = *(const bf16x8*)&Bs[(wn + i * 16 + lr) * 64 + kk + lg * 8];
      }
#pragma unroll
      for (int i = 0; i < 4; ++i)
#pragma unroll
        for (int j = 0; j < 4; ++j)
          acc[i][j] = __builtin_amdgcn_mfma_f32_16x16x32_bf16(af[i], bfr[j], acc[i][j], 0, 0, 0);
    }
    __syncthreads();
  }
#pragma unroll
  for (int i = 0; i < 4; ++i) {
#pragma unroll
    for (int j = 0; j < 4; ++j) {
      int col = n0 + wn + j * 16 + lr;
      float bv = bias[col];
#pragma unroll
      for (int q = 0; q < 4; ++q) {
        int row = m0 + wm + i * 16 + lg * 4 + q;
        C[(size_t)row * N + col] = f2bf(acc[i][j][q] + bv);
      }
    }
  }
}

// stage 32 rows x 512 cols bf16 (row stride 512) into LDS, XOR-swizzled.
// PLAIN cached loads (R10/R11-proven safe & fast for write-once NT-stored h).
__device__ __forceinline__ void stage32r(char* dst, const u16* src, int tid) {
  const u64* s64 = (const u64*)src;
#pragma unroll
  for (int i = 0; i < 8; ++i) {
    int e = i * 512 + tid, r = e >> 7, c8 = e & 127;
    u64 v = s64[(size_t)r * 128 + c8];
    *(u64*)(dst + r * 1024 + ((((c8 >> 1) ^ (r & 7)) << 4) | ((c8 & 1) << 3))) = v;
  }
}

// ---------------- fused dual-chain wavefront recurrence, v5 ----------------
// 256 blocks (cooperative, 1/CU), 512 threads. Tile: 32 batch rows x 32 hid cols.
//   bid [0,128):   L1 — h1(t) = act(Xpre(t) + R1 h1(t-1)),         K=512
//   bid [128,256): L2 — h2(t) = act(W2 h1(t) + R2 h2(t-1) + b2)
// Block = (m8 = lb&7 -> rows [m8*32,+32), j16 = lb>>3 -> cols [j16*32,+32)).
// 8 waves = (gate g = w&3, kh = w>>2). L1: kh = K-half of R1 (8 ksteps each).
// L2: kh selects the MATRIX — kh=0: W2 (consumes As1=h1(t)), kh=1: R2 (As2=
// h2(t-1)); the kh-partial Gs sum implements the [W2|R2] concat for free.
// Changes vs R11 (passed, 838us):
//  (1) fan per hop 32 -> 16 producers; staged slab 64KB -> 32KB (x2 for L2).
//  (2) aggregated counter sync: producers atomicAdd cnt[t][m8]; consumer polls
//      ONE address for ==16 instead of 32 flags.
//  (3) Gs in separate LDS (no As overlay) -> 4 barriers/step instead of 5.
__global__ __launch_bounds__(512, 2) void lstm_duo3(
    const u16* __restrict__ Xpre,    // (S,256,2048) bf16, includes b1
    u16* __restrict__ H1,            // (S,256,512)
    u16* __restrict__ H2,            // (S,256,512)
    const u16* __restrict__ R1b,     // (2048,512)
    const u16* __restrict__ W2b,     // (2048,512)
    const u16* __restrict__ R2b,     // (2048,512)
    const float* __restrict__ b2,    // (2048,)
    u32* __restrict__ cnt1, u32* __restrict__ cnt2) {   // [SEQ][8] counters
  __shared__ __align__(16) char As1[32 * 1024];          // 32KB h slab
  __shared__ __align__(16) char As2[32 * 1024];          // 32KB (L2 only)
  __shared__ float Gsf[2 * 4 * 32 * 33];                 // 33KB kh-partial gates
  const int tid = threadIdx.x;
  const int lane = tid & 63;
  const int w = tid >> 6;
  const int lr = lane & 15, lg = lane >> 4;
  const int kind = blockIdx.x >> 7;            // 0=L1, 1=L2
  const int lb = blockIdx.x & 127;
  const int m8 = lb & 7, j16 = lb >> 3;
  const int m0 = m8 * 32, j0 = j16 * 32;
  const int g = w & 3, kh = w >> 2;
  const int cr = tid >> 4, cc = (tid & 15) * 2;   // epilogue: cell (row cr, cols cc,cc+1)
#define GS(KH, GG, RR, CC) Gsf[(((KH) * 4 + (GG)) * 32 + (RR)) * 33 + (CC)]

  if (kind == 0) {
    // =========================== L1 chain ===========================
    // weights: gate g, cols j0 + nf*16 + lr, K-half kh (8 ksteps) -> 64 VGPR
    bf16x8 B1[2][8];
#pragma unroll
    for (int nf = 0; nf < 2; ++nf)
#pragma unroll
      for (int k = 0; k < 8; ++k)
        B1[nf][k] = *(const bf16x8*)&R1b[(size_t)(g * 512 + j0 + nf * 16 + lr) * 512 +
                                         kh * 256 + k * 32 + lg * 8];
    float cst0 = 0.f, cst1 = 0.f;

    for (int t = 0; t < SEQ_; ++t) {
      // prefetch Xpre(t) (read-only, plain loads; hides under poll)
      u32 xp[4];
#pragma unroll
      for (int gg = 0; gg < 4; ++gg)
        xp[gg] = *(const u32*)(Xpre + (size_t)t * (BATCH_ * NG_) +
                               (size_t)(m0 + cr) * NG_ + gg * 512 + j0 + cc);
      if (t > 0) {
        if (w == 0 && lane == 0) {   // single-address counter poll
          const u32* f = cnt1 + (size_t)(t - 1) * 8 + m8;
          int spins = 0;
          while (aload32(f) < 16u) {
            __builtin_amdgcn_s_sleep(1);
            if (++spins > (1 << 21)) break;
          }
        }
        __syncthreads();
        stage32r(As1, H1 + ((size_t)(t - 1) * BATCH_ + m0) * HID_, tid);
      }
      __syncthreads();
      f32x4 acc[2][2] = {};
      if (t > 0) {
#pragma unroll
        for (int k = 0; k < 8; ++k) {
          int c = kh * 32 + k * 4 + lg;
          int sw = ((c ^ (lr & 7)) << 4);
          bf16x8 a0 = *(const bf16x8*)(As1 + (lr) * 1024 + sw);
          bf16x8 a1 = *(const bf16x8*)(As1 + (16 + lr) * 1024 + sw);
          acc[0][0] = __builtin_amdgcn_mfma_f32_16x16x32_bf16(a0, B1[0][k], acc[0][0], 0, 0, 0);
          acc[0][1] = __builtin_amdgcn_mfma_f32_16x16x32_bf16(a0, B1[1][k], acc[0][1], 0, 0, 0);
          acc[1][0] = __builtin_amdgcn_mfma_f32_16x16x32_bf16(a1, B1[0][k], acc[1][0], 0, 0, 0);
          acc[1][1] = __builtin_amdgcn_mfma_f32_16x16x32_bf16(a1, B1[1][k], acc[1][1], 0, 0, 0);
        }
      }
      // publish kh-partials (C/D: col=lane&15, row=(lane>>4)*4+q)
#pragma unroll
      for (int mf = 0; mf < 2; ++mf)
#pragma unroll
        for (int nf = 0; nf < 2; ++nf)
#pragma unroll
          for (int q = 0; q < 4; ++q)
            GS(kh, g, mf * 16 + lg * 4 + q, nf * 16 + lr) = acc[mf][nf][q];
      __syncthreads();
      {  // cell update: thread owns (cr, cc..cc+1)
        float G[4][2];
#pragma unroll
        for (int gg = 0; gg < 4; ++gg) {
          G[gg][0] = GS(0, gg, cr, cc) + GS(1, gg, cr, cc) + bf2f((u16)xp[gg]);
          G[gg][1] = GS(0, gg, cr, cc + 1) + GS(1, gg, cr, cc + 1) + bf2f((u16)(xp[gg] >> 16));
        }
        u32 pack = 0;
        {
          float iv = 1.f / (1.f + expf(-G[0][0]));
          float fv = 1.f / (1.f + expf(-G[1][0]));
          float mv = tanhf(G[2][0]);
          float ov = 1.f / (1.f + expf(-G[3][0]));
          float cn = mv * iv + fv * cst0; cst0 = cn;
          pack |= (u32)f2bf(ov * tanhf(cn));
        }
        {
          float iv = 1.f / (1.f + expf(-G[0][1]));
          float fv = 1.f / (1.f + expf(-G[1][1]));
          float mv = tanhf(G[2][1]);
          float ov = 1.f / (1.f + expf(-G[3][1]));
          float cn = mv * iv + fv * cst1; cst1 = cn;
          pack |= (u32)f2bf(ov * tanhf(cn)) << 16;
        }
        astore32((u32*)(H1 + (size_t)t * (BATCH_ * HID_) +
                        (size_t)(m0 + cr) * HID_ + j0 + cc), pack);  // NT -> MALL
      }
      __syncthreads();   // vmcnt(0) drain: all h stores at MALL before counter add
      if (tid == 0)
        __hip_atomic_fetch_add(cnt1 + (size_t)t * 8 + m8, 1u,
                               __ATOMIC_RELAXED, __HIP_MEMORY_SCOPE_AGENT);
    }
  } else {
    // =========================== L2 chain ===========================
    // kh=0: W2 full-K (As1 = h1(t));  kh=1: R2 full-K (As2 = h2(t-1)). 128 VGPR.
    const u16* Bmat = kh ? R2b : W2b;
    bf16x8 Bw[2][16];
#pragma unroll
    for (int nf = 0; nf < 2; ++nf)
#pragma unroll
      for (int k = 0; k < 16; ++k)
        Bw[nf][k] = *(const bf16x8*)&Bmat[(size_t)(g * 512 + j0 + nf * 16 + lr) * 512 +
                                          k * 32 + lg * 8];
    float bc[4][2];
#pragma unroll
    for (int gg = 0; gg < 4; ++gg) {
      bc[gg][0] = b2[gg * 512 + j0 + cc];
      bc[gg][1] = b2[gg * 512 + j0 + cc + 1];
    }
    float cst0 = 0.f, cst1 = 0.f;

    for (int t = 0; t < SEQ_; ++t) {
      // combined counter poll: lane0 cnt1[t] (h1 ready), lane1 cnt2[t-1] (self)
      if (w == 0) {
        const u32* fa = cnt1 + (size_t)t * 8 + m8;
        const u32* fb = cnt2 + (size_t)(t > 0 ? t - 1 : 0) * 8 + m8;
        int spins = 0;
        while (true) {
          bool ok = true;
          if (lane == 0) ok = aload32(fa) >= 16u;
          else if (lane == 1) ok = (t == 0) || (aload32(fb) >= 16u);
          if (__all(ok)) break;
          __builtin_amdgcn_s_sleep(1);
          if (++spins > (1 << 21)) break;
        }
      }
      __syncthreads();
      stage32r(As1, H1 + ((size_t)t * BATCH_ + m0) * HID_, tid);
      if (t > 0)
        stage32r(As2, H2 + ((size_t)(t - 1) * BATCH_ + m0) * HID_, tid);
      __syncthreads();
      f32x4 acc[2][2] = {};
      if (kh == 0 || t > 0) {
        const char* As = kh ? As2 : As1;
#pragma unroll
        for (int k = 0; k < 16; ++k) {
          int c = k * 4 + lg;
          int sw = ((c ^ (lr & 7)) << 4);
          bf16x8 a0 = *(const bf16x8*)(As + (lr) * 1024 + sw);
          bf16x8 a1 = *(const bf16x8*)(As + (16 + lr) * 1024 + sw);
          acc[0][0] = __builtin_amdgcn_mfma_f32_16x16x32_bf16(a0, Bw[0][k], acc[0][0], 0, 0, 0);
          acc[0][1] = __builtin_amdgcn_mfma_f32_16x16x32_bf16(a0, Bw[1][k], acc[0][1], 0, 0, 0);
          acc[1][0] = __builtin_amdgcn_mfma_f32_16x16x32_bf16(a1, Bw[0][k], acc[1][0], 0, 0, 0);
          acc[1][1] = __builtin_amdgcn_mfma_f32_16x16x32_bf16(a1, Bw[1][k], acc[1][1], 0, 0, 0);
        }
      }
#pragma unroll
      for (int mf = 0; mf < 2; ++mf)
#pragma unroll
        for (int nf = 0; nf < 2; ++nf)
#pragma unroll
          for (int q = 0; q < 4; ++q)
            GS(kh, g, mf * 16 + lg * 4 + q, nf * 16 + lr) = acc[mf][nf][q];
      __syncthreads();
      {
        float G[4][2];
#pragma unroll
        for (int gg = 0; gg < 4; ++gg) {
          G[gg][0] = GS(0, gg, cr, cc) + GS(1, gg, cr, cc) + bc[gg][0];
          G[gg][1] = GS(0, gg, cr, cc + 1) + GS(1, gg, cr, cc + 1) + bc[gg][1];
        }
        u32 pack = 0;
        {
          float iv = 1.f / (1.f + expf(-G[0][0]));
          float fv = 1.f / (1.f + expf(-G[1][0]));
          float mv = tanhf(G[2][0]);
          float ov = 1.f / (1.f + expf(-G[3][0]));
          float cn = mv * iv + fv * cst0; cst0 = cn;
          pack |= (u32)f2bf(ov * tanhf(cn));
        }
        {
          float iv = 1.f / (1.f + expf(-G[0][1]));
          float fv = 1.f / (1.f + expf(-G[1][1]));
          float mv = tanhf(G[2][1]);
          float ov = 1.f / (1.f + expf(-G[3][1]));
          float cn = mv * iv + fv * cst1; cst1 = cn;
          pack |= (u32)f2bf(ov * tanhf(cn)) << 16;
        }
        astore32((u32*)(H2 + (size_t)t * (BATCH_ * HID_) +
                        (size_t)(m0 + cr) * HID_ + j0 + cc), pack);
      }
      __syncthreads();
      if (tid == 0)
        __hip_atomic_fetch_add(cnt2 + (size_t)t * 8 + m8, 1u,
                               __ATOMIC_RELAXED, __HIP_MEMORY_SCOPE_AGENT);
    }
  }
#undef GS
}

// ---------------- output projection: out[b][t][cls] = h2 . Wo[cls] + bo ----------------
__global__ __launch_bounds__(320) void out_proj(const u16* __restrict__ H2,
                                                const float* __restrict__ Wo,
                                                const float* __restrict__ bo,
                                                float* __restrict__ out) {
  __shared__ __align__(16) u16 Hs[32 * 520];
  const int r0 = blockIdx.x * 32;     // flat row = t*256 + b
  const int tid = threadIdx.x;
  for (int e = tid; e < 2048; e += 320) {
    int rl = e >> 6, k8 = (e & 63) * 8;
    *(uint4*)&Hs[rl * 520 + k8] = *(const uint4*)(H2 + (size_t)(r0 + rl) * HID_ + k8);
  }
  __syncthreads();
  if (tid < 288) {
    int rl = tid / 9, cls = tid - rl * 9;
    const u16* h = &Hs[rl * 520];
    const float* wv = Wo + cls * HID_;
    float s = bo[cls];
#pragma unroll 8
    for (int k = 0; k < HID_; ++k) s += bf2f(h[k]) * wv[k];
    int r = r0 + rl, t = r >> 8, b = r & 255;
    out[((size_t)b * SEQ_ + t) * NCLS_ + cls] = s;
  }
}

extern "C" void kernel_launch(void* const* d_in, const int* in_sizes, int n_in,
                              void* d_out, int out_size, void* d_ws, size_t ws_size,
                              hipStream_t stream) {
  (void)in_sizes; (void)n_in; (void)out_size; (void)ws_size;
  const int*   ids = (const int*)d_in[0];
  const float* tok = (const float*)d_in[1];
  const float* pos = (const float*)d_in[2];
  const float* W1  = (const float*)d_in[3];
  const float* R1  = (const float*)d_in[4];
  const float* b1  = (const float*)d_in[5];
  const float* W2  = (const float*)d_in[6];
  const float* R2  = (const float*)d_in[7];
  const float* b2  = (const float*)d_in[8];
  const float* Wo  = (const float*)d_in[9];
  const float* bo  = (const float*)d_in[10];
  float* out = (float*)d_out;

  // workspace (~226 MB); H1all overlays Xbf (dead after phase A)
  char* p = (char*)d_ws;
  auto alloc = [&](size_t bytes) { char* q = p; p += (bytes + 255) & ~(size_t)255; return q; };
  u16*  W1b  = (u16*)alloc((size_t)NG_ * DIN_ * 2);                 // 3MB
  u16*  R1b  = (u16*)alloc((size_t)NG_ * HID_ * 2);                 // 2MB
  u16*  W2b  = (u16*)alloc((size_t)NG_ * HID_ * 2);                 // 2MB
  u16*  R2b  = (u16*)alloc((size_t)NG_ * HID_ * 2);                 // 2MB
  u32*  cnt1 = (u32*)alloc((size_t)SEQ_ * 8 * 4);                   // 4KB
  u32*  cnt2 = (u32*)alloc((size_t)SEQ_ * 8 * 4);                   // 4KB
  size_t xbf_bytes = (size_t)SEQ_ * BATCH_ * DIN_ * 2;              // 50.3MB
  u16*  Xbf  = (u16*)alloc(xbf_bytes);
  u16*  H1all = Xbf;                                                // overlay (32MB < 50.3MB)
  u16*  H2all = (u16*)alloc((size_t)SEQ_ * BATCH_ * HID_ * 2);      // 32MB
  u16*  Xpre = (u16*)alloc((size_t)SEQ_ * BATCH_ * NG_ * 2);        // 134MB

  // weight casts
  castk<<<dim3((NG_ * DIN_ / 4 + 255) / 256), 256, 0, stream>>>(W1, W1b, NG_ * DIN_ / 4);
  castk<<<dim3((NG_ * HID_ / 4 + 255) / 256), 256, 0, stream>>>(R1, R1b, NG_ * HID_ / 4);
  castk<<<dim3((NG_ * HID_ / 4 + 255) / 256), 256, 0, stream>>>(W2, W2b, NG_ * HID_ / 4);
  castk<<<dim3((NG_ * HID_ / 4 + 255) / 256), 256, 0, stream>>>(R2, R2b, NG_ * HID_ / 4);
  // counters must be zero each call (graph replays re-run this memset)
  hipMemsetAsync(cnt1, 0, (size_t)2 * SEQ_ * 8 * 4, stream);  // cnt1+cnt2 contiguous

  // embeds -> (S,B,768) bf16
  embed_k<<<dim3(SEQ_ * BATCH_), 192, 0, stream>>>(ids, tok, pos, Xbf);

  // phase A: Xpre = X @ W1^T + b1   (32768 x 2048, K=768)
  gemm_bt<<<dim3(NG_ / 128, SEQ_ * BATCH_ / 128), 256, 0, stream>>>(
      Xbf, W1b, b1, Xpre, SEQ_ * BATCH_, NG_, DIN_);

  // fused dual-chain recurrence (cooperative: co-residency for spin-wait)
  {
    const u16* Xp = Xpre; u16* H1a = H1all; u16* H2a = H2all;
    const u16* R1a = R1b; const u16* W2a = W2b; const u16* R2a = R2b;
    const float* b2a = b2;
    u32* c1 = cnt1; u32* c2 = cnt2;
    void* args[] = {(void*)&Xp, (void*)&H1a, (void*)&H2a, (void*)&R1a,
                    (void*)&W2a, (void*)&R2a, (void*)&b2a, (void*)&c1, (void*)&c2};
    hipLaunchCooperativeKernel(reinterpret_cast<void*>(&lstm_duo3),
                               dim3(256), dim3(512), args, 0, stream);
  }

  // logits
  out_proj<<<dim3(SEQ_ * BATCH_ / 32), 320, 0, stream>>>(H2all, Wo, bo, out);
}